// Round 2
// baseline (1078.079 us; speedup 1.0000x reference)
//
#include <hip/hip_runtime.h>
#include <math.h>

#define BATCH 2
#define LSEQ  2048
#define TTOK  4096
#define DM    1024
#define DI    2048
#define NH    32
#define HP    64
#define NS    128
#define CONVD 2304
#define PROJ  4384
#define NCH   32
#define BLK   64

__device__ __forceinline__ float silu_(float x) { return x / (1.f + __expf(-x)); }

// ---------------- GEMM: C[M,N] = A[M,K] * Bw[N,K]^T (+ optional residual R[M,N]) ----------------
template<int HASRES>
__global__ __launch_bounds__(256, 2)
void sgemm_nt(const float* __restrict__ A, const float* __restrict__ Bw,
              float* __restrict__ C, const float* __restrict__ R,
              int M, int N, int K)
{
    __shared__ float As[8][128];
    __shared__ float Bs[8][128];
    const int t  = threadIdx.x;
    const int tx = t & 15, ty = t >> 4;
    const int bm = blockIdx.y * 128, bn = blockIdx.x * 128;
    const int lrow = t >> 1;
    const int lh   = (t & 1) * 4;
    const bool aok = (bm + lrow) < M;
    const bool bok = (bn + lrow) < N;
    const float* Ap = A  + (size_t)(bm + lrow) * K + lh;
    const float* Bp = Bw + (size_t)(bn + lrow) * K + lh;

    float acc[8][8];
#pragma unroll
    for (int i = 0; i < 8; ++i)
#pragma unroll
        for (int j = 0; j < 8; ++j) acc[i][j] = 0.f;

    for (int k0 = 0; k0 < K; k0 += 8) {
        float4 av = make_float4(0.f,0.f,0.f,0.f), bv = make_float4(0.f,0.f,0.f,0.f);
        if (aok) av = *(const float4*)(Ap + k0);
        if (bok) bv = *(const float4*)(Bp + k0);
        __syncthreads();
        As[lh+0][lrow]=av.x; As[lh+1][lrow]=av.y; As[lh+2][lrow]=av.z; As[lh+3][lrow]=av.w;
        Bs[lh+0][lrow]=bv.x; Bs[lh+1][lrow]=bv.y; Bs[lh+2][lrow]=bv.z; Bs[lh+3][lrow]=bv.w;
        __syncthreads();
#pragma unroll
        for (int k = 0; k < 8; ++k) {
            float4 a0 = *(const float4*)&As[k][ty*4];
            float4 a1 = *(const float4*)&As[k][64+ty*4];
            float4 b0 = *(const float4*)&Bs[k][tx*4];
            float4 b1 = *(const float4*)&Bs[k][64+tx*4];
            float a[8] = {a0.x,a0.y,a0.z,a0.w,a1.x,a1.y,a1.z,a1.w};
            float b[8] = {b0.x,b0.y,b0.z,b0.w,b1.x,b1.y,b1.z,b1.w};
#pragma unroll
            for (int i = 0; i < 8; ++i)
#pragma unroll
                for (int j = 0; j < 8; ++j)
                    acc[i][j] = fmaf(a[i], b[j], acc[i][j]);
        }
    }
#pragma unroll
    for (int i = 0; i < 8; ++i) {
        int m = bm + ((i < 4) ? (ty*4 + i) : (64 + ty*4 + i - 4));
        if (m >= M) continue;
#pragma unroll
        for (int j = 0; j < 8; ++j) {
            int n = bn + ((j < 4) ? (tx*4 + j) : (64 + tx*4 + j - 4));
            if (n >= N) continue;
            float v = acc[i][j];
            if (HASRES) v += R[(size_t)m * N + n];
            C[(size_t)m * N + n] = v;
        }
    }
}

// ---------------- depthwise causal conv (K=4) + DOUBLE silu ----------------
// Reference applies silu to conv output, then silu AGAIN on each split (x, B, C).
__global__ __launch_bounds__(256)
void conv_silu_k(const float* __restrict__ zx, const float* __restrict__ cw,
                 float* __restrict__ out)
{
    int idx = blockIdx.x * 256 + threadIdx.x;   // TTOK*CONVD
    int c  = idx % CONVD;
    int tk = idx / CONVD;
    int b = tk >> 11, l = tk & 2047;
    const float* col = zx + (size_t)b * LSEQ * PROJ + DI + c;
    const float* w = cw + c * 4;
    float acc = w[3] * col[(size_t)l * PROJ];
    if (l >= 1) acc += w[2] * col[(size_t)(l-1) * PROJ];
    if (l >= 2) acc += w[1] * col[(size_t)(l-2) * PROJ];
    if (l >= 3) acc += w[0] * col[(size_t)(l-3) * PROJ];
    out[idx] = silu_(silu_(acc));
}

// ---------------- dt = softplus(dt_raw + bias) ----------------
__global__ __launch_bounds__(256)
void dt_k(const float* __restrict__ zx, const float* __restrict__ dt_bias,
          float* __restrict__ dt_sp)
{
    int idx = blockIdx.x * 256 + threadIdx.x;   // TTOK*NH
    int h = idx & 31, tk = idx >> 5;
    float x = zx[(size_t)tk * PROJ + (DI + CONVD) + h] + dt_bias[h];
    dt_sp[idx] = (x > 20.f) ? x : log1pf(expf(x));
}

// ---------------- per-chunk cumulative sum of A*dt ----------------
__global__ __launch_bounds__(256)
void cuma_k(const float* __restrict__ dt_sp, const float* __restrict__ A_log,
            float* __restrict__ cumA)
{
    int idx = blockIdx.x * 256 + threadIdx.x;   // BATCH*NH*NCH = 2048 ; idx = b*1024 + h*32 + c
    if (idx >= BATCH*NH*NCH) return;
    int c = idx & 31, h = (idx >> 5) & 31, b = idx >> 10;
    float negA = -expf(A_log[h]);
    int tk0 = b * LSEQ + c * BLK;
    float run = 0.f;
    float* o = cumA + (size_t)idx * 64;
    for (int l = 0; l < 64; ++l) {
        run += negA * dt_sp[(tk0 + l) * NH + h];
        o[l] = run;
    }
}

// ---------------- CBT[l,s] = sum_n C[l,n]*B[s,n]  (head-independent, ngroups=1) ----------------
__global__ __launch_bounds__(256)
void cbt_k(const float* __restrict__ xBCs, float* __restrict__ CBT)
{
    int b = blockIdx.x >> 5, c = blockIdx.x & 31;
    __shared__ float sB[64][65];
    __shared__ float sC[64][65];
    int t = threadIdx.x, r = t >> 2, q = t & 3;
    const float* xb = xBCs + (size_t)(b * LSEQ + c * BLK) * CONVD;
    float acc[16];
#pragma unroll
    for (int i = 0; i < 16; ++i) acc[i] = 0.f;
    for (int half = 0; half < 2; ++half) {
        __syncthreads();
#pragma unroll
        for (int jj = 0; jj < 4; ++jj) {
            float4 bv = *(const float4*)(xb + (size_t)r * CONVD + DI      + half*64 + q*16 + jj*4);
            float4 cv = *(const float4*)(xb + (size_t)r * CONVD + DI + NS + half*64 + q*16 + jj*4);
            int col = q*16 + jj*4;
            sB[r][col]=bv.x; sB[r][col+1]=bv.y; sB[r][col+2]=bv.z; sB[r][col+3]=bv.w;
            sC[r][col]=cv.x; sC[r][col+1]=cv.y; sC[r][col+2]=cv.z; sC[r][col+3]=cv.w;
        }
        __syncthreads();
        for (int n = 0; n < 64; ++n) {
            float cv = sC[r][n];
#pragma unroll
            for (int si = 0; si < 16; ++si)
                acc[si] += cv * sB[q*16 + si][n];
        }
    }
    float* o = CBT + (size_t)blockIdx.x * 4096 + r * 64 + q * 16;
#pragma unroll
    for (int si = 0; si < 16; ++si) o[si] = acc[si];
}

// ---------------- chunk states[p,n] = sum_l decay[l]*B[l,n]*Xdt[l,p] ----------------
__global__ __launch_bounds__(256)
void states_k(const float* __restrict__ xBCs, const float* __restrict__ dt_sp,
              const float* __restrict__ cumA, float* __restrict__ states)
{
    int bi = blockIdx.x;                 // b*1024 + c*32 + h
    int h = bi & 31, c = (bi >> 5) & 31, b = bi >> 10;
    __shared__ float sXd[64][68];
    __shared__ float sBd[64][132];
    int t = threadIdx.x, r = t >> 2, q = t & 3;
    const float* cA = cumA + (size_t)((b*NH + h)*NCH + c) * 64;
    float lastA = cA[63];
    float dec = expf(lastA - cA[r]);
    int tk = b * LSEQ + c * BLK + r;
    float dtv = dt_sp[tk * NH + h];
    const float* xb = xBCs + (size_t)tk * CONVD;
#pragma unroll
    for (int jj = 0; jj < 4; ++jj) {
        float4 v = *(const float4*)(xb + h*HP + q*16 + jj*4);
        int col = q*16 + jj*4;
        sXd[r][col]=v.x*dtv; sXd[r][col+1]=v.y*dtv; sXd[r][col+2]=v.z*dtv; sXd[r][col+3]=v.w*dtv;
    }
#pragma unroll
    for (int jj = 0; jj < 8; ++jj) {
        float4 v = *(const float4*)(xb + DI + q*32 + jj*4);
        int col = q*32 + jj*4;
        sBd[r][col]=v.x*dec; sBd[r][col+1]=v.y*dec; sBd[r][col+2]=v.z*dec; sBd[r][col+3]=v.w*dec;
    }
    __syncthreads();
    int txn = t & 31, typ = t >> 5;       // n0 = txn*4, p0 = typ*8
    float acc[8][4];
#pragma unroll
    for (int i = 0; i < 8; ++i)
#pragma unroll
        for (int j = 0; j < 4; ++j) acc[i][j] = 0.f;
    for (int l = 0; l < 64; ++l) {
        float4 x0 = *(const float4*)&sXd[l][typ*8];
        float4 x1 = *(const float4*)&sXd[l][typ*8+4];
        float4 bv = *(const float4*)&sBd[l][txn*4];
        float xv[8] = {x0.x,x0.y,x0.z,x0.w,x1.x,x1.y,x1.z,x1.w};
        float bb[4] = {bv.x,bv.y,bv.z,bv.w};
#pragma unroll
        for (int i = 0; i < 8; ++i)
#pragma unroll
            for (int j = 0; j < 4; ++j) acc[i][j] = fmaf(xv[i], bb[j], acc[i][j]);
    }
    float* o = states + (size_t)((b*NCH + c)*NH + h) * (HP*NS);
#pragma unroll
    for (int i = 0; i < 8; ++i)
        *(float4*)(o + (typ*8 + i)*NS + txn*4) = make_float4(acc[i][0],acc[i][1],acc[i][2],acc[i][3]);
}

// ---------------- inter-chunk scan (overwrites states with incoming state; writes final state) ---
__global__ __launch_bounds__(256)
void scan_k(const float* __restrict__ init_state, const float* __restrict__ cumA,
            float* __restrict__ states, float* __restrict__ out_final)
{
    int idx = blockIdx.x * 256 + threadIdx.x;   // BATCH*NH*HP*NS = 524288
    int h = (idx >> 13) & 31, b = idx >> 18;
    int pn = idx & 8191;
    float run = init_state[idx];
    const float* cAb = cumA + (size_t)(b*NH + h) * NCH * 64;
    for (int c = 0; c < NCH; ++c) {
        float la = cAb[c*64 + 63];
        float* sp = states + (size_t)((b*NCH + c)*NH + h) * 8192 + pn;
        float tmp = *sp;
        *sp = run;
        run = expf(la) * run + tmp;
    }
    out_final[idx] = run;
}

// ---------------- Y = Y_diag + Y_off + D*X ----------------
__global__ __launch_bounds__(256)
void y_k(const float* __restrict__ xBCs, const float* __restrict__ dt_sp,
         const float* __restrict__ cumA, const float* __restrict__ CBT,
         const float* __restrict__ states, const float* __restrict__ D_param,
         float* __restrict__ Y)
{
    int bi = blockIdx.x;                 // b*1024 + c*32 + h
    int h = bi & 31, c = (bi >> 5) & 31, b = bi >> 10;
    __shared__ float LA[64][68];
    __shared__ float LB[64][68];
    __shared__ float sCA[64];
    int t = threadIdx.x, r = t >> 2, q = t & 3;
    int l = r, pb = q * 16;
    const float* cA = cumA + (size_t)((b*NH + h)*NCH + c) * 64;
    if (t < 64) sCA[t] = cA[t];
    int tk = b * LSEQ + c * BLK + r;
    const float* xb = xBCs + (size_t)tk * CONVD;
    float dtv = dt_sp[tk * NH + h];
    const float* cbt = CBT + (size_t)(b*NCH + c) * 4096;
#pragma unroll
    for (int jj = 0; jj < 4; ++jj) {
        float4 v = *(const float4*)(xb + h*HP + q*16 + jj*4);
        int col = q*16 + jj*4;
        LA[r][col]=v.x*dtv; LA[r][col+1]=v.y*dtv; LA[r][col+2]=v.z*dtv; LA[r][col+3]=v.w*dtv;
        float4 w = *(const float4*)(cbt + r*64 + q*16 + jj*4);
        LB[r][col]=w.x; LB[r][col+1]=w.y; LB[r][col+2]=w.z; LB[r][col+3]=w.w;
    }
    __syncthreads();
    float acc[16], acc2[16];
#pragma unroll
    for (int i = 0; i < 16; ++i) { acc[i]=0.f; acc2[i]=0.f; }
    float mycA = sCA[l];
    for (int s = 0; s <= l; ++s) {
        float w = LB[l][s] * __expf(mycA - sCA[s]);
        const float* xs = &LA[s][pb];
        float4 x0 = *(const float4*)(xs);
        float4 x1 = *(const float4*)(xs+4);
        float4 x2 = *(const float4*)(xs+8);
        float4 x3 = *(const float4*)(xs+12);
        acc[0] +=w*x0.x; acc[1] +=w*x0.y; acc[2] +=w*x0.z; acc[3] +=w*x0.w;
        acc[4] +=w*x1.x; acc[5] +=w*x1.y; acc[6] +=w*x1.z; acc[7] +=w*x1.w;
        acc[8] +=w*x2.x; acc[9] +=w*x2.y; acc[10]+=w*x2.z; acc[11]+=w*x2.w;
        acc[12]+=w*x3.x; acc[13]+=w*x3.y; acc[14]+=w*x3.z; acc[15]+=w*x3.w;
    }
    const float* stp = states + (size_t)((b*NCH + c)*NH + h) * 8192;
    for (int half = 0; half < 2; ++half) {
        __syncthreads();
#pragma unroll
        for (int jj = 0; jj < 4; ++jj) {
            float4 v = *(const float4*)(stp + r*NS + half*64 + q*16 + jj*4);
            int col = q*16 + jj*4;
            LA[col  ][r]=v.x; LA[col+1][r]=v.y; LA[col+2][r]=v.z; LA[col+3][r]=v.w;   // transpose
            float4 w = *(const float4*)(xb + DI + NS + half*64 + q*16 + jj*4);
            LB[r][col]=w.x; LB[r][col+1]=w.y; LB[r][col+2]=w.z; LB[r][col+3]=w.w;
        }
        __syncthreads();
        for (int n2 = 0; n2 < 64; ++n2) {
            float cl = LB[l][n2];
            const float* ss = &LA[n2][pb];
            float4 s0 = *(const float4*)(ss);
            float4 s1 = *(const float4*)(ss+4);
            float4 s2 = *(const float4*)(ss+8);
            float4 s3 = *(const float4*)(ss+12);
            acc2[0] +=cl*s0.x; acc2[1] +=cl*s0.y; acc2[2] +=cl*s0.z; acc2[3] +=cl*s0.w;
            acc2[4] +=cl*s1.x; acc2[5] +=cl*s1.y; acc2[6] +=cl*s1.z; acc2[7] +=cl*s1.w;
            acc2[8] +=cl*s2.x; acc2[9] +=cl*s2.y; acc2[10]+=cl*s2.z; acc2[11]+=cl*s2.w;
            acc2[12]+=cl*s3.x; acc2[13]+=cl*s3.y; acc2[14]+=cl*s3.z; acc2[15]+=cl*s3.w;
        }
    }
    float eC = __expf(mycA);
    float Dh = D_param[h];
    float* yo = Y + (size_t)tk * DI + h*HP + pb;
#pragma unroll
    for (int jj = 0; jj < 4; ++jj) {
        float4 xr = *(const float4*)(xb + h*HP + pb + jj*4);
        float4 o;
        o.x = acc[jj*4+0] + eC*acc2[jj*4+0] + Dh*xr.x;
        o.y = acc[jj*4+1] + eC*acc2[jj*4+1] + Dh*xr.y;
        o.z = acc[jj*4+2] + eC*acc2[jj*4+2] + Dh*xr.z;
        o.w = acc[jj*4+3] + eC*acc2[jj*4+3] + Dh*xr.w;
        *(float4*)(yo + jj*4) = o;
    }
}

// ---------------- RMSNorm + sigmoid(z) gate, in place on Y ----------------
__global__ __launch_bounds__(256)
void rms_gate_k(const float* __restrict__ zx, const float* __restrict__ norm_w,
                float* __restrict__ Y)
{
    int tk = blockIdx.x, t = threadIdx.x;
    float* row = Y + (size_t)tk * DI;
    float4 v0 = *(const float4*)(row + t*4);
    float4 v1 = *(const float4*)(row + 1024 + t*4);
    float ss = v0.x*v0.x + v0.y*v0.y + v0.z*v0.z + v0.w*v0.w
             + v1.x*v1.x + v1.y*v1.y + v1.z*v1.z + v1.w*v1.w;
#pragma unroll
    for (int off = 32; off > 0; off >>= 1) ss += __shfl_xor(ss, off, 64);
    __shared__ float sw[4];
    __shared__ float stot;
    if ((t & 63) == 0) sw[t >> 6] = ss;
    __syncthreads();
    if (t == 0) stot = rsqrtf((sw[0]+sw[1]+sw[2]+sw[3]) * (1.f/DI) + 1.1920929e-07f);
    __syncthreads();
    float scale = stot;
    const float* zr = zx + (size_t)tk * PROJ;
    float4 z0 = *(const float4*)(zr + t*4);
    float4 z1 = *(const float4*)(zr + 1024 + t*4);
    float4 w0 = *(const float4*)(norm_w + t*4);
    float4 w1 = *(const float4*)(norm_w + 1024 + t*4);
    float4 o0, o1;
    o0.x = v0.x*scale*w0.x / (1.f+__expf(-z0.x));
    o0.y = v0.y*scale*w0.y / (1.f+__expf(-z0.y));
    o0.z = v0.z*scale*w0.z / (1.f+__expf(-z0.z));
    o0.w = v0.w*scale*w0.w / (1.f+__expf(-z0.w));
    o1.x = v1.x*scale*w1.x / (1.f+__expf(-z1.x));
    o1.y = v1.y*scale*w1.y / (1.f+__expf(-z1.y));
    o1.z = v1.z*scale*w1.z / (1.f+__expf(-z1.z));
    o1.w = v1.w*scale*w1.w / (1.f+__expf(-z1.w));
    *(float4*)(row + t*4) = o0;
    *(float4*)(row + 1024 + t*4) = o1;
}

extern "C" void kernel_launch(void* const* d_in, const int* in_sizes, int n_in,
                              void* d_out, int out_size, void* d_ws, size_t ws_size,
                              hipStream_t stream)
{
    const float* x        = (const float*)d_in[0];
    const float* init_st  = (const float*)d_in[1];
    const float* in_proj  = (const float*)d_in[2];
    const float* conv_w   = (const float*)d_in[3];
    const float* A_log    = (const float*)d_in[4];
    const float* dt_bias  = (const float*)d_in[5];
    const float* D_param  = (const float*)d_in[6];
    const float* norm_w   = (const float*)d_in[7];
    const float* out_proj = (const float*)d_in[8];
    float* out = (float*)d_out;

    float* ws     = (float*)d_ws;
    float* zx     = ws;                                   // TTOK*PROJ
    float* xBCs   = zx     + (size_t)TTOK*PROJ;           // TTOK*CONVD
    float* dt_sp  = xBCs   + (size_t)TTOK*CONVD;          // TTOK*NH
    float* cumA   = dt_sp  + (size_t)TTOK*NH;             // BATCH*NH*NCH*64
    float* CBTb   = cumA   + (size_t)BATCH*NH*NCH*64;     // BATCH*NCH*4096
    float* states = CBTb   + (size_t)BATCH*NCH*4096;      // BATCH*NCH*NH*HP*NS
    float* Yb     = states + (size_t)BATCH*NCH*NH*HP*NS;  // TTOK*DI

    // 1. zxbcdt = x @ in_proj^T   (4096 x 4384, K=1024)
    sgemm_nt<0><<<dim3((PROJ+127)/128, TTOK/128), 256, 0, stream>>>(x, in_proj, zx, nullptr, TTOK, PROJ, DM);
    // 2. depthwise causal conv + double silu
    conv_silu_k<<<(TTOK*CONVD)/256, 256, 0, stream>>>(zx, conv_w, xBCs);
    // 3. dt = softplus(dt_raw + bias)
    dt_k<<<(TTOK*NH)/256, 256, 0, stream>>>(zx, dt_bias, dt_sp);
    // 4. per-chunk cumsum of A*dt
    cuma_k<<<(BATCH*NH*NCH + 255)/256, 256, 0, stream>>>(dt_sp, A_log, cumA);
    // 5. CB^T per (b,c)
    cbt_k<<<BATCH*NCH, 256, 0, stream>>>(xBCs, CBTb);
    // 6. intra-chunk states
    states_k<<<BATCH*NCH*NH, 256, 0, stream>>>(xBCs, dt_sp, cumA, states);
    // 7. inter-chunk scan (also writes final_state to d_out tail)
    scan_k<<<(BATCH*NH*HP*NS)/256, 256, 0, stream>>>(init_st, cumA, states, out + (size_t)TTOK*DM);
    // 8. Y = Y_diag + Y_off + D*X
    y_k<<<BATCH*NCH*NH, 256, 0, stream>>>(xBCs, dt_sp, cumA, CBTb, states, D_param, Yb);
    // 9. RMSNorm + gate (in place)
    rms_gate_k<<<TTOK, 256, 0, stream>>>(zx, norm_w, Yb);
    // 10. y = y_core @ out_proj^T + x
    sgemm_nt<1><<<dim3(DM/128, TTOK/128), 256, 0, stream>>>(Yb, out_proj, out, x, TTOK, DM, DI);
}

// Round 3
// 433.756 us; speedup vs baseline: 2.4855x; 2.4855x over previous
//
#include <hip/hip_runtime.h>
#include <math.h>

#define BATCH 2
#define LSEQ  2048
#define TTOK  4096
#define DM    1024
#define DI    2048
#define NH    32
#define HP    64
#define NS    128
#define CONVD 2304
#define PROJ  4384
#define NCH   32
#define BLK   64

typedef __bf16 bf16x8 __attribute__((ext_vector_type(8)));
typedef float  f32x4  __attribute__((ext_vector_type(4)));
typedef unsigned short ushortx8 __attribute__((ext_vector_type(8)));
typedef __attribute__((address_space(3))) void  lds_void;
typedef __attribute__((address_space(1))) const void glb_cvoid;

__device__ __forceinline__ float silu_(float x) { return x / (1.f + __expf(-x)); }

__device__ __forceinline__ unsigned short f2bf(float x) {
    union { float f; unsigned u; } u; u.f = x;
    unsigned r = u.u + 0x7fffu + ((u.u >> 16) & 1u);   // RNE
    return (unsigned short)(r >> 16);
}

// ---------------- fp32 -> bf16 cast (8 elems/thread) ----------------
__global__ __launch_bounds__(256)
void cast_bf16_k(const float* __restrict__ in, unsigned short* __restrict__ out, int n)
{
    int i = (blockIdx.x * 256 + threadIdx.x) * 8;
    if (i >= n) return;
    float4 a = *(const float4*)(in + i);
    float4 b = *(const float4*)(in + i + 4);
    ushortx8 r;
    r[0]=f2bf(a.x); r[1]=f2bf(a.y); r[2]=f2bf(a.z); r[3]=f2bf(a.w);
    r[4]=f2bf(b.x); r[5]=f2bf(b.y); r[6]=f2bf(b.z); r[7]=f2bf(b.w);
    *(ushortx8*)(out + i) = r;
}

// ---------------- bf16 MFMA GEMM: C[M,N] = A[M,K] * Bw[N,K]^T (+R), fp32 out ----------------
// 128x128 tile, 4 waves (2x2 of 64x64), 16x16x32 bf16 MFMA, global_load_lds width-16 staging.
template<int HASRES>
__global__ __launch_bounds__(256)
void hgemm_nt(const unsigned short* __restrict__ A, const unsigned short* __restrict__ Bw,
              float* __restrict__ C, const float* __restrict__ R,
              int M, int N, int K)
{
    __shared__ unsigned short As[128 * 32];
    __shared__ unsigned short Bs[128 * 32];
    const int t = threadIdx.x;
    const int l = t & 63, w = t >> 6;
    const int bm = blockIdx.y * 128, bn = blockIdx.x * 128;
    const int wm = (w >> 1) * 64, wn = (w & 1) * 64;

    // staging: thread t loads rows (t>>2) and 64+(t>>2), k-quarter (t&3)*8
    const int srow = t >> 2;
    const int skk  = (t & 3) * 8;
    const unsigned short* Ag0 = A + (size_t)(bm + srow)      * K + skk;
    const unsigned short* Ag1 = A + (size_t)(bm + 64 + srow) * K + skk;
    const int bn0 = min(bn + srow, N - 1), bn1 = min(bn + 64 + srow, N - 1);
    const unsigned short* Bg0 = Bw + (size_t)bn0 * K + skk;
    const unsigned short* Bg1 = Bw + (size_t)bn1 * K + skk;
    // LDS byte offsets: (row*32 + kk)*2 == 16*t (+4096 for second row) -> wave-uniform base + lane*16
    char* As0 = (char*)As;
    char* Bs0 = (char*)Bs;
    const int la0 = 16 * t;
    const int la1 = 4096 + 16 * t;

    f32x4 acc[4][4] = {};
    const int fr = l & 15, koff = (l >> 4) * 8;

    for (int k0 = 0; k0 < K; k0 += 32) {
        __syncthreads();
        __builtin_amdgcn_global_load_lds((glb_cvoid*)(Ag0 + k0), (lds_void*)(As0 + la0), 16, 0, 0);
        __builtin_amdgcn_global_load_lds((glb_cvoid*)(Ag1 + k0), (lds_void*)(As0 + la1), 16, 0, 0);
        __builtin_amdgcn_global_load_lds((glb_cvoid*)(Bg0 + k0), (lds_void*)(Bs0 + la0), 16, 0, 0);
        __builtin_amdgcn_global_load_lds((glb_cvoid*)(Bg1 + k0), (lds_void*)(Bs0 + la1), 16, 0, 0);
        __syncthreads();
        bf16x8 af[4], bfr[4];
#pragma unroll
        for (int mt = 0; mt < 4; ++mt)
            af[mt] = *(const bf16x8*)(As + (wm + mt * 16 + fr) * 32 + koff);
#pragma unroll
        for (int nt = 0; nt < 4; ++nt)
            bfr[nt] = *(const bf16x8*)(Bs + (wn + nt * 16 + fr) * 32 + koff);
#pragma unroll
        for (int mt = 0; mt < 4; ++mt)
#pragma unroll
            for (int nt = 0; nt < 4; ++nt)
                acc[mt][nt] = __builtin_amdgcn_mfma_f32_16x16x32_bf16(af[mt], bfr[nt], acc[mt][nt], 0, 0, 0);
    }

    const int crow = (l >> 4) * 4, ccol = l & 15;
#pragma unroll
    for (int mt = 0; mt < 4; ++mt) {
#pragma unroll
        for (int nt = 0; nt < 4; ++nt) {
            int n = bn + wn + nt * 16 + ccol;
            if (n >= N) continue;
#pragma unroll
            for (int i = 0; i < 4; ++i) {
                int m = bm + wm + mt * 16 + crow + i;
                float v = acc[mt][nt][i];
                if (HASRES) v += R[(size_t)m * N + n];
                C[(size_t)m * N + n] = v;
            }
        }
    }
}

// ---------------- depthwise causal conv (K=4) + double silu ----------------
__global__ __launch_bounds__(256)
void conv_silu_k(const float* __restrict__ zx, const float* __restrict__ cw,
                 float* __restrict__ out)
{
    int idx = blockIdx.x * 256 + threadIdx.x;   // TTOK*CONVD
    int c  = idx % CONVD;
    int tk = idx / CONVD;
    int b = tk >> 11, l = tk & 2047;
    const float* col = zx + (size_t)b * LSEQ * PROJ + DI + c;
    const float* w = cw + c * 4;
    float acc = w[3] * col[(size_t)l * PROJ];
    if (l >= 1) acc += w[2] * col[(size_t)(l-1) * PROJ];
    if (l >= 2) acc += w[1] * col[(size_t)(l-2) * PROJ];
    if (l >= 3) acc += w[0] * col[(size_t)(l-3) * PROJ];
    out[idx] = silu_(silu_(acc));
}

// ---------------- dt = softplus(dt_raw + bias) ----------------
__global__ __launch_bounds__(256)
void dt_k(const float* __restrict__ zx, const float* __restrict__ dt_bias,
          float* __restrict__ dt_sp)
{
    int idx = blockIdx.x * 256 + threadIdx.x;   // TTOK*NH
    int h = idx & 31, tk = idx >> 5;
    float x = zx[(size_t)tk * PROJ + (DI + CONVD) + h] + dt_bias[h];
    dt_sp[idx] = (x > 20.f) ? x : log1pf(expf(x));
}

// ---------------- per-chunk cumulative sum of A*dt ----------------
__global__ __launch_bounds__(256)
void cuma_k(const float* __restrict__ dt_sp, const float* __restrict__ A_log,
            float* __restrict__ cumA)
{
    int idx = blockIdx.x * 256 + threadIdx.x;   // BATCH*NH*NCH
    if (idx >= BATCH*NH*NCH) return;
    int c = idx & 31, h = (idx >> 5) & 31, b = idx >> 10;
    float negA = -expf(A_log[h]);
    int tk0 = b * LSEQ + c * BLK;
    float run = 0.f;
    float* o = cumA + (size_t)idx * 64;
    for (int l = 0; l < 64; ++l) {
        run += negA * dt_sp[(tk0 + l) * NH + h];
        o[l] = run;
    }
}

// ---------------- CBT[l,s] = sum_n C[l,n]*B[s,n] ----------------
__global__ __launch_bounds__(256)
void cbt_k(const float* __restrict__ xBCs, float* __restrict__ CBT)
{
    int b = blockIdx.x >> 5, c = blockIdx.x & 31;
    __shared__ float sB[64][65];
    __shared__ float sC[64][65];
    int t = threadIdx.x, r = t >> 2, q = t & 3;
    const float* xb = xBCs + (size_t)(b * LSEQ + c * BLK) * CONVD;
    float acc[16];
#pragma unroll
    for (int i = 0; i < 16; ++i) acc[i] = 0.f;
    for (int half = 0; half < 2; ++half) {
        __syncthreads();
#pragma unroll
        for (int jj = 0; jj < 4; ++jj) {
            float4 bv = *(const float4*)(xb + (size_t)r * CONVD + DI      + half*64 + q*16 + jj*4);
            float4 cv = *(const float4*)(xb + (size_t)r * CONVD + DI + NS + half*64 + q*16 + jj*4);
            int col = q*16 + jj*4;
            sB[r][col]=bv.x; sB[r][col+1]=bv.y; sB[r][col+2]=bv.z; sB[r][col+3]=bv.w;
            sC[r][col]=cv.x; sC[r][col+1]=cv.y; sC[r][col+2]=cv.z; sC[r][col+3]=cv.w;
        }
        __syncthreads();
        for (int n = 0; n < 64; ++n) {
            float cv = sC[r][n];
#pragma unroll
            for (int si = 0; si < 16; ++si)
                acc[si] += cv * sB[q*16 + si][n];
        }
    }
    float* o = CBT + (size_t)blockIdx.x * 4096 + r * 64 + q * 16;
#pragma unroll
    for (int si = 0; si < 16; ++si) o[si] = acc[si];
}

// ---------------- chunk states[p,n] = sum_l decay[l]*B[l,n]*Xdt[l,p] ----------------
__global__ __launch_bounds__(256)
void states_k(const float* __restrict__ xBCs, const float* __restrict__ dt_sp,
              const float* __restrict__ cumA, float* __restrict__ states)
{
    int bi = blockIdx.x;                 // b*1024 + c*32 + h
    int h = bi & 31, c = (bi >> 5) & 31, b = bi >> 10;
    __shared__ float sXd[64][68];
    __shared__ float sBd[64][132];
    int t = threadIdx.x, r = t >> 2, q = t & 3;
    const float* cA = cumA + (size_t)((b*NH + h)*NCH + c) * 64;
    float lastA = cA[63];
    float dec = expf(lastA - cA[r]);
    int tk = b * LSEQ + c * BLK + r;
    float dtv = dt_sp[tk * NH + h];
    const float* xb = xBCs + (size_t)tk * CONVD;
#pragma unroll
    for (int jj = 0; jj < 4; ++jj) {
        float4 v = *(const float4*)(xb + h*HP + q*16 + jj*4);
        int col = q*16 + jj*4;
        sXd[r][col]=v.x*dtv; sXd[r][col+1]=v.y*dtv; sXd[r][col+2]=v.z*dtv; sXd[r][col+3]=v.w*dtv;
    }
#pragma unroll
    for (int jj = 0; jj < 8; ++jj) {
        float4 v = *(const float4*)(xb + DI + q*32 + jj*4);
        int col = q*32 + jj*4;
        sBd[r][col]=v.x*dec; sBd[r][col+1]=v.y*dec; sBd[r][col+2]=v.z*dec; sBd[r][col+3]=v.w*dec;
    }
    __syncthreads();
    int txn = t & 31, typ = t >> 5;
    float acc[8][4];
#pragma unroll
    for (int i = 0; i < 8; ++i)
#pragma unroll
        for (int j = 0; j < 4; ++j) acc[i][j] = 0.f;
    for (int l = 0; l < 64; ++l) {
        float4 x0 = *(const float4*)&sXd[l][typ*8];
        float4 x1 = *(const float4*)&sXd[l][typ*8+4];
        float4 bv = *(const float4*)&sBd[l][txn*4];
        float xv[8] = {x0.x,x0.y,x0.z,x0.w,x1.x,x1.y,x1.z,x1.w};
        float bb[4] = {bv.x,bv.y,bv.z,bv.w};
#pragma unroll
        for (int i = 0; i < 8; ++i)
#pragma unroll
            for (int j = 0; j < 4; ++j) acc[i][j] = fmaf(xv[i], bb[j], acc[i][j]);
    }
    float* o = states + (size_t)((b*NCH + c)*NH + h) * (HP*NS);
#pragma unroll
    for (int i = 0; i < 8; ++i)
        *(float4*)(o + (typ*8 + i)*NS + txn*4) = make_float4(acc[i][0],acc[i][1],acc[i][2],acc[i][3]);
}

// ---------------- inter-chunk scan ----------------
__global__ __launch_bounds__(256)
void scan_k(const float* __restrict__ init_state, const float* __restrict__ cumA,
            float* __restrict__ states, float* __restrict__ out_final)
{
    int idx = blockIdx.x * 256 + threadIdx.x;   // BATCH*NH*HP*NS
    int h = (idx >> 13) & 31, b = idx >> 18;
    int pn = idx & 8191;
    float run = init_state[idx];
    const float* cAb = cumA + (size_t)(b*NH + h) * NCH * 64;
    for (int c = 0; c < NCH; ++c) {
        float la = cAb[c*64 + 63];
        float* sp = states + (size_t)((b*NCH + c)*NH + h) * 8192 + pn;
        float tmp = *sp;
        *sp = run;
        run = expf(la) * run + tmp;
    }
    out_final[idx] = run;
}

// ---------------- Y = Y_diag + Y_off + D*X ----------------
__global__ __launch_bounds__(256)
void y_k(const float* __restrict__ xBCs, const float* __restrict__ dt_sp,
         const float* __restrict__ cumA, const float* __restrict__ CBT,
         const float* __restrict__ states, const float* __restrict__ D_param,
         float* __restrict__ Y)
{
    int bi = blockIdx.x;                 // b*1024 + c*32 + h
    int h = bi & 31, c = (bi >> 5) & 31, b = bi >> 10;
    __shared__ float LA[64][68];
    __shared__ float LB[64][68];
    __shared__ float sCA[64];
    int t = threadIdx.x, r = t >> 2, q = t & 3;
    int l = r, pb = q * 16;
    const float* cA = cumA + (size_t)((b*NH + h)*NCH + c) * 64;
    if (t < 64) sCA[t] = cA[t];
    int tk = b * LSEQ + c * BLK + r;
    const float* xb = xBCs + (size_t)tk * CONVD;
    float dtv = dt_sp[tk * NH + h];
    const float* cbt = CBT + (size_t)(b*NCH + c) * 4096;
#pragma unroll
    for (int jj = 0; jj < 4; ++jj) {
        float4 v = *(const float4*)(xb + h*HP + q*16 + jj*4);
        int col = q*16 + jj*4;
        LA[r][col]=v.x*dtv; LA[r][col+1]=v.y*dtv; LA[r][col+2]=v.z*dtv; LA[r][col+3]=v.w*dtv;
        float4 w = *(const float4*)(cbt + r*64 + q*16 + jj*4);
        LB[r][col]=w.x; LB[r][col+1]=w.y; LB[r][col+2]=w.z; LB[r][col+3]=w.w;
    }
    __syncthreads();
    float acc[16], acc2[16];
#pragma unroll
    for (int i = 0; i < 16; ++i) { acc[i]=0.f; acc2[i]=0.f; }
    float mycA = sCA[l];
    for (int s = 0; s <= l; ++s) {
        float w = LB[l][s] * __expf(mycA - sCA[s]);
        const float* xs = &LA[s][pb];
        float4 x0 = *(const float4*)(xs);
        float4 x1 = *(const float4*)(xs+4);
        float4 x2 = *(const float4*)(xs+8);
        float4 x3 = *(const float4*)(xs+12);
        acc[0] +=w*x0.x; acc[1] +=w*x0.y; acc[2] +=w*x0.z; acc[3] +=w*x0.w;
        acc[4] +=w*x1.x; acc[5] +=w*x1.y; acc[6] +=w*x1.z; acc[7] +=w*x1.w;
        acc[8] +=w*x2.x; acc[9] +=w*x2.y; acc[10]+=w*x2.z; acc[11]+=w*x2.w;
        acc[12]+=w*x3.x; acc[13]+=w*x3.y; acc[14]+=w*x3.z; acc[15]+=w*x3.w;
    }
    const float* stp = states + (size_t)((b*NCH + c)*NH + h) * 8192;
    for (int half = 0; half < 2; ++half) {
        __syncthreads();
#pragma unroll
        for (int jj = 0; jj < 4; ++jj) {
            float4 v = *(const float4*)(stp + r*NS + half*64 + q*16 + jj*4);
            int col = q*16 + jj*4;
            LA[col  ][r]=v.x; LA[col+1][r]=v.y; LA[col+2][r]=v.z; LA[col+3][r]=v.w;   // transpose
            float4 w = *(const float4*)(xb + DI + NS + half*64 + q*16 + jj*4);
            LB[r][col]=w.x; LB[r][col+1]=w.y; LB[r][col+2]=w.z; LB[r][col+3]=w.w;
        }
        __syncthreads();
        for (int n2 = 0; n2 < 64; ++n2) {
            float cl = LB[l][n2];
            const float* ss = &LA[n2][pb];
            float4 s0 = *(const float4*)(ss);
            float4 s1 = *(const float4*)(ss+4);
            float4 s2 = *(const float4*)(ss+8);
            float4 s3 = *(const float4*)(ss+12);
            acc2[0] +=cl*s0.x; acc2[1] +=cl*s0.y; acc2[2] +=cl*s0.z; acc2[3] +=cl*s0.w;
            acc2[4] +=cl*s1.x; acc2[5] +=cl*s1.y; acc2[6] +=cl*s1.z; acc2[7] +=cl*s1.w;
            acc2[8] +=cl*s2.x; acc2[9] +=cl*s2.y; acc2[10]+=cl*s2.z; acc2[11]+=cl*s2.w;
            acc2[12]+=cl*s3.x; acc2[13]+=cl*s3.y; acc2[14]+=cl*s3.z; acc2[15]+=cl*s3.w;
        }
    }
    float eC = __expf(mycA);
    float Dh = D_param[h];
    float* yo = Y + (size_t)tk * DI + h*HP + pb;
#pragma unroll
    for (int jj = 0; jj < 4; ++jj) {
        float4 xr = *(const float4*)(xb + h*HP + pb + jj*4);
        float4 o;
        o.x = acc[jj*4+0] + eC*acc2[jj*4+0] + Dh*xr.x;
        o.y = acc[jj*4+1] + eC*acc2[jj*4+1] + Dh*xr.y;
        o.z = acc[jj*4+2] + eC*acc2[jj*4+2] + Dh*xr.z;
        o.w = acc[jj*4+3] + eC*acc2[jj*4+3] + Dh*xr.w;
        *(float4*)(yo + jj*4) = o;
    }
}

// ---------------- RMSNorm + sigmoid(z) gate -> bf16 ----------------
__global__ __launch_bounds__(256)
void rms_gate_k(const float* __restrict__ zx, const float* __restrict__ norm_w,
                const float* __restrict__ Y, unsigned short* __restrict__ Yb)
{
    int tk = blockIdx.x, t = threadIdx.x;
    const float* row = Y + (size_t)tk * DI;
    float4 v0 = *(const float4*)(row + t*4);
    float4 v1 = *(const float4*)(row + 1024 + t*4);
    float ss = v0.x*v0.x + v0.y*v0.y + v0.z*v0.z + v0.w*v0.w
             + v1.x*v1.x + v1.y*v1.y + v1.z*v1.z + v1.w*v1.w;
#pragma unroll
    for (int off = 32; off > 0; off >>= 1) ss += __shfl_xor(ss, off, 64);
    __shared__ float sw[4];
    __shared__ float stot;
    if ((t & 63) == 0) sw[t >> 6] = ss;
    __syncthreads();
    if (t == 0) stot = rsqrtf((sw[0]+sw[1]+sw[2]+sw[3]) * (1.f/DI) + 1.1920929e-07f);
    __syncthreads();
    float scale = stot;
    const float* zr = zx + (size_t)tk * PROJ;
    float4 z0 = *(const float4*)(zr + t*4);
    float4 z1 = *(const float4*)(zr + 1024 + t*4);
    float4 w0 = *(const float4*)(norm_w + t*4);
    float4 w1 = *(const float4*)(norm_w + 1024 + t*4);
    ushort4 o0, o1;
    o0.x = f2bf(v0.x*scale*w0.x / (1.f+__expf(-z0.x)));
    o0.y = f2bf(v0.y*scale*w0.y / (1.f+__expf(-z0.y)));
    o0.z = f2bf(v0.z*scale*w0.z / (1.f+__expf(-z0.z)));
    o0.w = f2bf(v0.w*scale*w0.w / (1.f+__expf(-z0.w)));
    o1.x = f2bf(v1.x*scale*w1.x / (1.f+__expf(-z1.x)));
    o1.y = f2bf(v1.y*scale*w1.y / (1.f+__expf(-z1.y)));
    o1.z = f2bf(v1.z*scale*w1.z / (1.f+__expf(-z1.z)));
    o1.w = f2bf(v1.w*scale*w1.w / (1.f+__expf(-z1.w)));
    *(ushort4*)(Yb + (size_t)tk * DI + t*4) = o0;
    *(ushort4*)(Yb + (size_t)tk * DI + 1024 + t*4) = o1;
}

extern "C" void kernel_launch(void* const* d_in, const int* in_sizes, int n_in,
                              void* d_out, int out_size, void* d_ws, size_t ws_size,
                              hipStream_t stream)
{
    const float* x        = (const float*)d_in[0];
    const float* init_st  = (const float*)d_in[1];
    const float* in_proj  = (const float*)d_in[2];
    const float* conv_w   = (const float*)d_in[3];
    const float* A_log    = (const float*)d_in[4];
    const float* dt_bias  = (const float*)d_in[5];
    const float* D_param  = (const float*)d_in[6];
    const float* norm_w   = (const float*)d_in[7];
    const float* out_proj = (const float*)d_in[8];
    float* out = (float*)d_out;

    float* ws     = (float*)d_ws;
    float* zx     = ws;                                   // TTOK*PROJ
    float* xBCs   = zx     + (size_t)TTOK*PROJ;           // TTOK*CONVD
    float* dt_sp  = xBCs   + (size_t)TTOK*CONVD;          // TTOK*NH
    float* cumA   = dt_sp  + (size_t)TTOK*NH;             // BATCH*NH*NCH*64
    float* CBTb   = cumA   + (size_t)BATCH*NH*NCH*64;     // BATCH*NCH*4096
    float* states = CBTb   + (size_t)BATCH*NCH*4096;      // BATCH*NCH*NH*HP*NS
    float* Yb     = states + (size_t)BATCH*NCH*NH*HP*NS;  // TTOK*DI

    // bf16 aliases over dead regions:
    unsigned short* xb_bf  = (unsigned short*)Yb;                         // TTOK*DM (dead until y_k)
    unsigned short* ipw_bf = (unsigned short*)(Yb + (size_t)TTOK*DM/2);   // PROJ*DM
    unsigned short* opw_bf = (unsigned short*)states;                     // DM*DI (after y_k)
    unsigned short* Yb_bf  = (unsigned short*)xBCs;                       // TTOK*DI (after y_k)

    // 0. casts for GEMM1
    cast_bf16_k<<<(TTOK*DM)/(256*8), 256, 0, stream>>>(x, xb_bf, TTOK*DM);
    cast_bf16_k<<<(PROJ*DM)/(256*8), 256, 0, stream>>>(in_proj, ipw_bf, PROJ*DM);
    // 1. zxbcdt = x @ in_proj^T  (bf16 MFMA)
    hgemm_nt<0><<<dim3((PROJ+127)/128, TTOK/128), 256, 0, stream>>>(xb_bf, ipw_bf, zx, nullptr, TTOK, PROJ, DM);
    // 2. depthwise causal conv + double silu
    conv_silu_k<<<(TTOK*CONVD)/256, 256, 0, stream>>>(zx, conv_w, xBCs);
    // 3. dt = softplus(dt_raw + bias)
    dt_k<<<(TTOK*NH)/256, 256, 0, stream>>>(zx, dt_bias, dt_sp);
    // 4. per-chunk cumsum of A*dt
    cuma_k<<<(BATCH*NH*NCH + 255)/256, 256, 0, stream>>>(dt_sp, A_log, cumA);
    // 5. CB^T per (b,c)
    cbt_k<<<BATCH*NCH, 256, 0, stream>>>(xBCs, CBTb);
    // 6. intra-chunk states
    states_k<<<BATCH*NCH*NH, 256, 0, stream>>>(xBCs, dt_sp, cumA, states);
    // 7. inter-chunk scan
    scan_k<<<(BATCH*NH*HP*NS)/256, 256, 0, stream>>>(init_st, cumA, states, out + (size_t)TTOK*DM);
    // 8. Y = Y_diag + Y_off + D*X   (last reader of xBCs & states)
    y_k<<<BATCH*NCH*NH, 256, 0, stream>>>(xBCs, dt_sp, cumA, CBTb, states, D_param, Yb);
    // 8.5 cast out_proj (into dead states region)
    cast_bf16_k<<<(DM*DI)/(256*8), 256, 0, stream>>>(out_proj, opw_bf, DM*DI);
    // 9. RMSNorm + gate -> bf16 (into dead xBCs region)
    rms_gate_k<<<TTOK, 256, 0, stream>>>(zx, norm_w, Yb, Yb_bf);
    // 10. y = y_core @ out_proj^T + x  (bf16 MFMA + fp32 residual)
    hgemm_nt<1><<<dim3(DM/128, TTOK/128), 256, 0, stream>>>(Yb_bf, opw_bf, out, x, TTOK, DM, DI);
}

// Round 4
// 396.199 us; speedup vs baseline: 2.7211x; 1.0948x over previous
//
#include <hip/hip_runtime.h>
#include <math.h>

#define BATCH 2
#define LSEQ  2048
#define TTOK  4096
#define DM    1024
#define DI    2048
#define NH    32
#define HP    64
#define NS    128
#define CONVD 2304
#define PROJ  4384
#define NCH   32
#define BLK   64

typedef __bf16 bf16x8 __attribute__((ext_vector_type(8)));
typedef float  f32x4  __attribute__((ext_vector_type(4)));
typedef unsigned short ushortx8 __attribute__((ext_vector_type(8)));
typedef __attribute__((address_space(3))) void  lds_void;
typedef __attribute__((address_space(1))) const void glb_cvoid;

__device__ __forceinline__ float silu_(float x) { return x / (1.f + __expf(-x)); }

__device__ __forceinline__ unsigned short f2bf(float x) {
    union { float f; unsigned u; } u; u.f = x;
    unsigned r = u.u + 0x7fffu + ((u.u >> 16) & 1u);   // RNE
    return (unsigned short)(r >> 16);
}

// ---------------- fp32 -> bf16 cast (8 elems/thread) ----------------
__global__ __launch_bounds__(256)
void cast_bf16_k(const float* __restrict__ in, unsigned short* __restrict__ out, int n)
{
    int i = (blockIdx.x * 256 + threadIdx.x) * 8;
    if (i >= n) return;
    float4 a = *(const float4*)(in + i);
    float4 b = *(const float4*)(in + i + 4);
    ushortx8 r;
    r[0]=f2bf(a.x); r[1]=f2bf(a.y); r[2]=f2bf(a.z); r[3]=f2bf(a.w);
    r[4]=f2bf(b.x); r[5]=f2bf(b.y); r[6]=f2bf(b.z); r[7]=f2bf(b.w);
    *(ushortx8*)(out + i) = r;
}

// ---------------- bf16 MFMA GEMM: C[M,N] = A[M,K] * Bw[N,K]^T (+R), fp32 out ----------------
template<int HASRES>
__global__ __launch_bounds__(256)
void hgemm_nt(const unsigned short* __restrict__ A, const unsigned short* __restrict__ Bw,
              float* __restrict__ C, const float* __restrict__ R,
              int M, int N, int K)
{
    __shared__ unsigned short As[128 * 32];
    __shared__ unsigned short Bs[128 * 32];
    const int t = threadIdx.x;
    const int l = t & 63, w = t >> 6;
    const int bm = blockIdx.y * 128, bn = blockIdx.x * 128;
    const int wm = (w >> 1) * 64, wn = (w & 1) * 64;

    const int srow = t >> 2;
    const int skk  = (t & 3) * 8;
    const unsigned short* Ag0 = A + (size_t)(bm + srow)      * K + skk;
    const unsigned short* Ag1 = A + (size_t)(bm + 64 + srow) * K + skk;
    const int bn0 = min(bn + srow, N - 1), bn1 = min(bn + 64 + srow, N - 1);
    const unsigned short* Bg0 = Bw + (size_t)bn0 * K + skk;
    const unsigned short* Bg1 = Bw + (size_t)bn1 * K + skk;
    char* As0 = (char*)As;
    char* Bs0 = (char*)Bs;
    const int la0 = 16 * t;
    const int la1 = 4096 + 16 * t;

    f32x4 acc[4][4] = {};
    const int fr = l & 15, koff = (l >> 4) * 8;

    for (int k0 = 0; k0 < K; k0 += 32) {
        __syncthreads();
        __builtin_amdgcn_global_load_lds((glb_cvoid*)(Ag0 + k0), (lds_void*)(As0 + la0), 16, 0, 0);
        __builtin_amdgcn_global_load_lds((glb_cvoid*)(Ag1 + k0), (lds_void*)(As0 + la1), 16, 0, 0);
        __builtin_amdgcn_global_load_lds((glb_cvoid*)(Bg0 + k0), (lds_void*)(Bs0 + la0), 16, 0, 0);
        __builtin_amdgcn_global_load_lds((glb_cvoid*)(Bg1 + k0), (lds_void*)(Bs0 + la1), 16, 0, 0);
        __syncthreads();
        bf16x8 af[4], bfr[4];
#pragma unroll
        for (int mt = 0; mt < 4; ++mt)
            af[mt] = *(const bf16x8*)(As + (wm + mt * 16 + fr) * 32 + koff);
#pragma unroll
        for (int nt = 0; nt < 4; ++nt)
            bfr[nt] = *(const bf16x8*)(Bs + (wn + nt * 16 + fr) * 32 + koff);
#pragma unroll
        for (int mt = 0; mt < 4; ++mt)
#pragma unroll
            for (int nt = 0; nt < 4; ++nt)
                acc[mt][nt] = __builtin_amdgcn_mfma_f32_16x16x32_bf16(af[mt], bfr[nt], acc[mt][nt], 0, 0, 0);
    }

    const int crow = (l >> 4) * 4, ccol = l & 15;
#pragma unroll
    for (int mt = 0; mt < 4; ++mt) {
#pragma unroll
        for (int nt = 0; nt < 4; ++nt) {
            int n = bn + wn + nt * 16 + ccol;
            if (n >= N) continue;
#pragma unroll
            for (int i = 0; i < 4; ++i) {
                int m = bm + wm + mt * 16 + crow + i;
                float v = acc[mt][nt][i];
                if (HASRES) v += R[(size_t)m * N + n];
                C[(size_t)m * N + n] = v;
            }
        }
    }
}

// ---------------- depthwise causal conv (K=4) + double silu ----------------
__global__ __launch_bounds__(256)
void conv_silu_k(const float* __restrict__ zx, const float* __restrict__ cw,
                 float* __restrict__ out)
{
    int idx = blockIdx.x * 256 + threadIdx.x;   // TTOK*CONVD
    int c  = idx % CONVD;
    int tk = idx / CONVD;
    int b = tk >> 11, l = tk & 2047;
    const float* col = zx + (size_t)b * LSEQ * PROJ + DI + c;
    const float* w = cw + c * 4;
    float acc = w[3] * col[(size_t)l * PROJ];
    if (l >= 1) acc += w[2] * col[(size_t)(l-1) * PROJ];
    if (l >= 2) acc += w[1] * col[(size_t)(l-2) * PROJ];
    if (l >= 3) acc += w[0] * col[(size_t)(l-3) * PROJ];
    out[idx] = silu_(silu_(acc));
}

// ---------------- fused dt=softplus + cumA prefix-sum (one wave per (b,h,c)) ----------------
__global__ __launch_bounds__(256)
void dtcuma_k(const float* __restrict__ zx, const float* __restrict__ dt_bias,
              const float* __restrict__ A_log, float* __restrict__ dt_sp,
              float* __restrict__ cumA)
{
    int wid = blockIdx.x * 4 + (threadIdx.x >> 6);   // b*1024 + h*32 + c
    int ln = threadIdx.x & 63;
    int c = wid & 31, h = (wid >> 5) & 31, b = wid >> 10;
    int tk = b * LSEQ + c * BLK + ln;
    float xv = zx[(size_t)tk * PROJ + (DI + CONVD) + h] + dt_bias[h];
    float dtv = (xv > 20.f) ? xv : log1pf(__expf(xv));
    dt_sp[tk * NH + h] = dtv;
    float val = -__expf(A_log[h]) * dtv;
#pragma unroll
    for (int off = 1; off < 64; off <<= 1) {
        float u = __shfl_up(val, off, 64);
        if (ln >= off) val += u;
    }
    cumA[(size_t)wid * 64 + ln] = val;
}

// ---------------- CBT[l,s] = sum_n C[l,n]*B[s,n] (head-independent) ----------------
__global__ __launch_bounds__(256)
void cbt_k(const float* __restrict__ xBCs, float* __restrict__ CBT)
{
    int b = blockIdx.x >> 5, c = blockIdx.x & 31;
    __shared__ float sB[64][65];
    __shared__ float sC[64][65];
    int t = threadIdx.x, r = t >> 2, q = t & 3;
    const float* xb = xBCs + (size_t)(b * LSEQ + c * BLK) * CONVD;
    float acc[16];
#pragma unroll
    for (int i = 0; i < 16; ++i) acc[i] = 0.f;
    for (int half = 0; half < 2; ++half) {
        __syncthreads();
#pragma unroll
        for (int jj = 0; jj < 4; ++jj) {
            float4 bv = *(const float4*)(xb + (size_t)r * CONVD + DI      + half*64 + q*16 + jj*4);
            float4 cv = *(const float4*)(xb + (size_t)r * CONVD + DI + NS + half*64 + q*16 + jj*4);
            int col = q*16 + jj*4;
            sB[r][col]=bv.x; sB[r][col+1]=bv.y; sB[r][col+2]=bv.z; sB[r][col+3]=bv.w;
            sC[r][col]=cv.x; sC[r][col+1]=cv.y; sC[r][col+2]=cv.z; sC[r][col+3]=cv.w;
        }
        __syncthreads();
        for (int n = 0; n < 64; ++n) {
            float cv = sC[r][n];
#pragma unroll
            for (int si = 0; si < 16; ++si)
                acc[si] += cv * sB[q*16 + si][n];
        }
    }
    float* o = CBT + (size_t)blockIdx.x * 4096 + r * 64 + q * 16;
#pragma unroll
    for (int si = 0; si < 16; ++si) o[si] = acc[si];
}

// ---------------- chunk states via MFMA: S[p,n] = sum_l Xd[l,p]*Bd[l,n] ----------------
__global__ __launch_bounds__(256)
void states_mfma_k(const float* __restrict__ xBCs, const float* __restrict__ dt_sp,
                   const float* __restrict__ cumA, float* __restrict__ states)
{
    int bi = blockIdx.x;                 // b*1024 + c*32 + h
    int h = bi & 31, c = (bi >> 5) & 31, b = bi >> 10;
    __shared__ unsigned short XdT[64 * 72];    // [p][l]
    __shared__ unsigned short BdT[128 * 72];   // [n][l]
    int t = threadIdx.x, r = t >> 2, q = t & 3;
    const float* cA = cumA + (size_t)((b*NH + h)*NCH + c) * 64;
    float dec = __expf(cA[63] - cA[r]);
    int tk = b * LSEQ + c * BLK + r;
    float dtv = dt_sp[tk * NH + h];
    const float* xb = xBCs + (size_t)tk * CONVD;
#pragma unroll
    for (int jj = 0; jj < 4; ++jj) {
        float4 v = *(const float4*)(xb + h*HP + q*16 + jj*4);
        int p0 = q*16 + jj*4;
        XdT[(p0+0)*72 + r] = f2bf(v.x*dtv);
        XdT[(p0+1)*72 + r] = f2bf(v.y*dtv);
        XdT[(p0+2)*72 + r] = f2bf(v.z*dtv);
        XdT[(p0+3)*72 + r] = f2bf(v.w*dtv);
    }
#pragma unroll
    for (int jj = 0; jj < 8; ++jj) {
        float4 v = *(const float4*)(xb + DI + q*32 + jj*4);
        int n0 = q*32 + jj*4;
        BdT[(n0+0)*72 + r] = f2bf(v.x*dec);
        BdT[(n0+1)*72 + r] = f2bf(v.y*dec);
        BdT[(n0+2)*72 + r] = f2bf(v.z*dec);
        BdT[(n0+3)*72 + r] = f2bf(v.w*dec);
    }
    __syncthreads();
    int ln = t & 63, w = t >> 6;
    int wm = (w >> 1) * 32, wn = (w & 1) * 64;   // p-span 32, n-span 64
    int fr = ln & 15;
    f32x4 acc[2][4] = {};
#pragma unroll
    for (int ks = 0; ks < 2; ++ks) {
        int koff = ks*32 + (ln >> 4) * 8;
        bf16x8 af[2], bv[4];
#pragma unroll
        for (int mt = 0; mt < 2; ++mt)
            af[mt] = *(const bf16x8*)&XdT[(wm + mt*16 + fr)*72 + koff];
#pragma unroll
        for (int nt = 0; nt < 4; ++nt)
            bv[nt] = *(const bf16x8*)&BdT[(wn + nt*16 + fr)*72 + koff];
#pragma unroll
        for (int mt = 0; mt < 2; ++mt)
#pragma unroll
            for (int nt = 0; nt < 4; ++nt)
                acc[mt][nt] = __builtin_amdgcn_mfma_f32_16x16x32_bf16(af[mt], bv[nt], acc[mt][nt], 0, 0, 0);
    }
    float* o = states + (size_t)((b*NCH + c)*NH + h) * 8192;
    int crow = (ln >> 4) * 4, ccol = ln & 15;
#pragma unroll
    for (int mt = 0; mt < 2; ++mt)
#pragma unroll
        for (int nt = 0; nt < 4; ++nt)
#pragma unroll
            for (int i = 0; i < 4; ++i)
                o[(wm + mt*16 + crow + i)*128 + wn + nt*16 + ccol] = acc[mt][nt][i];
}

// ---------------- inter-chunk scan ----------------
__global__ __launch_bounds__(256)
void scan_k(const float* __restrict__ init_state, const float* __restrict__ cumA,
            float* __restrict__ states, float* __restrict__ out_final)
{
    int idx = blockIdx.x * 256 + threadIdx.x;   // BATCH*NH*HP*NS
    int h = (idx >> 13) & 31, b = idx >> 18;
    int pn = idx & 8191;
    float run = init_state[idx];
    const float* cAb = cumA + (size_t)(b*NH + h) * NCH * 64;
    for (int c = 0; c < NCH; ++c) {
        float la = cAb[c*64 + 63];
        float* sp = states + (size_t)((b*NCH + c)*NH + h) * 8192 + pn;
        float tmp = *sp;
        *sp = run;
        run = expf(la) * run + tmp;
    }
    out_final[idx] = run;
}

// ---------------- Y = Y_diag + Y_off + D*X via MFMA ----------------
__global__ __launch_bounds__(256)
void y_mfma_k(const float* __restrict__ xBCs, const float* __restrict__ dt_sp,
              const float* __restrict__ cumA, const float* __restrict__ CBT,
              const float* __restrict__ states, const float* __restrict__ D_param,
              float* __restrict__ Y)
{
    int bi = blockIdx.x;                 // b*1024 + c*32 + h
    int h = bi & 31, c = (bi >> 5) & 31, b = bi >> 10;
    __shared__ unsigned short Wm[64 * 72];     // [l][s] masked decay*CBT
    __shared__ unsigned short XdT[64 * 72];    // [p][s]
    __shared__ unsigned short Cd[64 * 136];    // [l][n] C*exp(cA)
    __shared__ unsigned short Sp[64 * 136];    // [p][n] incoming state
    __shared__ float sCA[64];
    int t = threadIdx.x, r = t >> 2, q = t & 3;
    const float* cA = cumA + (size_t)((b*NH + h)*NCH + c) * 64;
    if (t < 64) sCA[t] = cA[t];
    __syncthreads();
    int tk = b * LSEQ + c * BLK + r;
    const float* xb = xBCs + (size_t)tk * CONVD;
    float dtv = dt_sp[tk * NH + h];
    float myA = sCA[r], eC = __expf(myA);
    const float* cbt = CBT + (size_t)(b*NCH + c) * 4096 + r * 64;
#pragma unroll
    for (int j = 0; j < 16; ++j) {
        int s = q*16 + j;
        float wv = (s <= r) ? cbt[s] * __expf(myA - sCA[s]) : 0.f;
        Wm[r*72 + s] = f2bf(wv);
    }
#pragma unroll
    for (int jj = 0; jj < 4; ++jj) {
        float4 v = *(const float4*)(xb + h*HP + q*16 + jj*4);
        int p0 = q*16 + jj*4;
        XdT[(p0+0)*72 + r] = f2bf(v.x*dtv);
        XdT[(p0+1)*72 + r] = f2bf(v.y*dtv);
        XdT[(p0+2)*72 + r] = f2bf(v.z*dtv);
        XdT[(p0+3)*72 + r] = f2bf(v.w*dtv);
    }
#pragma unroll
    for (int jj = 0; jj < 8; ++jj) {
        float4 v = *(const float4*)(xb + DI + NS + q*32 + jj*4);
        int n0 = q*32 + jj*4;
        Cd[r*136 + n0+0] = f2bf(v.x*eC);
        Cd[r*136 + n0+1] = f2bf(v.y*eC);
        Cd[r*136 + n0+2] = f2bf(v.z*eC);
        Cd[r*136 + n0+3] = f2bf(v.w*eC);
    }
    const float* stp = states + (size_t)((b*NCH + c)*NH + h) * 8192 + r * 128;
#pragma unroll
    for (int jj = 0; jj < 8; ++jj) {
        float4 v = *(const float4*)(stp + q*32 + jj*4);
        int n0 = q*32 + jj*4;
        Sp[r*136 + n0+0] = f2bf(v.x);
        Sp[r*136 + n0+1] = f2bf(v.y);
        Sp[r*136 + n0+2] = f2bf(v.z);
        Sp[r*136 + n0+3] = f2bf(v.w);
    }
    __syncthreads();
    int ln = t & 63, w = t >> 6;
    int wm = (w >> 1) * 32, wn = (w & 1) * 32;   // l-span 32, p-span 32
    int fr = ln & 15;
    f32x4 acc[2][2] = {};
#pragma unroll
    for (int ks = 0; ks < 2; ++ks) {            // Y_diag, K=64 (s)
        int koff = ks*32 + (ln >> 4) * 8;
        bf16x8 af[2], bv[2];
#pragma unroll
        for (int mt = 0; mt < 2; ++mt) af[mt] = *(const bf16x8*)&Wm[(wm + mt*16 + fr)*72 + koff];
#pragma unroll
        for (int nt = 0; nt < 2; ++nt) bv[nt] = *(const bf16x8*)&XdT[(wn + nt*16 + fr)*72 + koff];
#pragma unroll
        for (int mt = 0; mt < 2; ++mt)
#pragma unroll
            for (int nt = 0; nt < 2; ++nt)
                acc[mt][nt] = __builtin_amdgcn_mfma_f32_16x16x32_bf16(af[mt], bv[nt], acc[mt][nt], 0, 0, 0);
    }
#pragma unroll
    for (int ks = 0; ks < 4; ++ks) {            // Y_off, K=128 (n)
        int koff = ks*32 + (ln >> 4) * 8;
        bf16x8 af[2], bv[2];
#pragma unroll
        for (int mt = 0; mt < 2; ++mt) af[mt] = *(const bf16x8*)&Cd[(wm + mt*16 + fr)*136 + koff];
#pragma unroll
        for (int nt = 0; nt < 2; ++nt) bv[nt] = *(const bf16x8*)&Sp[(wn + nt*16 + fr)*136 + koff];
#pragma unroll
        for (int mt = 0; mt < 2; ++mt)
#pragma unroll
            for (int nt = 0; nt < 2; ++nt)
                acc[mt][nt] = __builtin_amdgcn_mfma_f32_16x16x32_bf16(af[mt], bv[nt], acc[mt][nt], 0, 0, 0);
    }
    float Dh = D_param[h];
    int crow = (ln >> 4) * 4, ccol = ln & 15;
#pragma unroll
    for (int mt = 0; mt < 2; ++mt)
#pragma unroll
        for (int nt = 0; nt < 2; ++nt)
#pragma unroll
            for (int i = 0; i < 4; ++i) {
                int li = wm + mt*16 + crow + i;
                int p  = wn + nt*16 + ccol;
                size_t row = (size_t)(b*LSEQ + c*BLK + li);
                float xv = xBCs[row * CONVD + h*HP + p];
                Y[row * DI + h*HP + p] = acc[mt][nt][i] + Dh * xv;
            }
}

// ---------------- RMSNorm + sigmoid(z) gate -> bf16 ----------------
__global__ __launch_bounds__(256)
void rms_gate_k(const float* __restrict__ zx, const float* __restrict__ norm_w,
                const float* __restrict__ Y, unsigned short* __restrict__ Yb)
{
    int tk = blockIdx.x, t = threadIdx.x;
    const float* row = Y + (size_t)tk * DI;
    float4 v0 = *(const float4*)(row + t*4);
    float4 v1 = *(const float4*)(row + 1024 + t*4);
    float ss = v0.x*v0.x + v0.y*v0.y + v0.z*v0.z + v0.w*v0.w
             + v1.x*v1.x + v1.y*v1.y + v1.z*v1.z + v1.w*v1.w;
#pragma unroll
    for (int off = 32; off > 0; off >>= 1) ss += __shfl_xor(ss, off, 64);
    __shared__ float sw[4];
    __shared__ float stot;
    if ((t & 63) == 0) sw[t >> 6] = ss;
    __syncthreads();
    if (t == 0) stot = rsqrtf((sw[0]+sw[1]+sw[2]+sw[3]) * (1.f/DI) + 1.1920929e-07f);
    __syncthreads();
    float scale = stot;
    const float* zr = zx + (size_t)tk * PROJ;
    float4 z0 = *(const float4*)(zr + t*4);
    float4 z1 = *(const float4*)(zr + 1024 + t*4);
    float4 w0 = *(const float4*)(norm_w + t*4);
    float4 w1 = *(const float4*)(norm_w + 1024 + t*4);
    ushort4 o0, o1;
    o0.x = f2bf(v0.x*scale*w0.x / (1.f+__expf(-z0.x)));
    o0.y = f2bf(v0.y*scale*w0.y / (1.f+__expf(-z0.y)));
    o0.z = f2bf(v0.z*scale*w0.z / (1.f+__expf(-z0.z)));
    o0.w = f2bf(v0.w*scale*w0.w / (1.f+__expf(-z0.w)));
    o1.x = f2bf(v1.x*scale*w1.x / (1.f+__expf(-z1.x)));
    o1.y = f2bf(v1.y*scale*w1.y / (1.f+__expf(-z1.y)));
    o1.z = f2bf(v1.z*scale*w1.z / (1.f+__expf(-z1.z)));
    o1.w = f2bf(v1.w*scale*w1.w / (1.f+__expf(-z1.w)));
    *(ushort4*)(Yb + (size_t)tk * DI + t*4) = o0;
    *(ushort4*)(Yb + (size_t)tk * DI + 1024 + t*4) = o1;
}

extern "C" void kernel_launch(void* const* d_in, const int* in_sizes, int n_in,
                              void* d_out, int out_size, void* d_ws, size_t ws_size,
                              hipStream_t stream)
{
    const float* x        = (const float*)d_in[0];
    const float* init_st  = (const float*)d_in[1];
    const float* in_proj  = (const float*)d_in[2];
    const float* conv_w   = (const float*)d_in[3];
    const float* A_log    = (const float*)d_in[4];
    const float* dt_bias  = (const float*)d_in[5];
    const float* D_param  = (const float*)d_in[6];
    const float* norm_w   = (const float*)d_in[7];
    const float* out_proj = (const float*)d_in[8];
    float* out = (float*)d_out;

    float* ws     = (float*)d_ws;
    float* zx     = ws;                                   // TTOK*PROJ
    float* xBCs   = zx     + (size_t)TTOK*PROJ;           // TTOK*CONVD
    float* dt_sp  = xBCs   + (size_t)TTOK*CONVD;          // TTOK*NH
    float* cumA   = dt_sp  + (size_t)TTOK*NH;             // BATCH*NH*NCH*64
    float* CBTb   = cumA   + (size_t)BATCH*NH*NCH*64;     // BATCH*NCH*4096
    float* states = CBTb   + (size_t)BATCH*NCH*4096;      // BATCH*NCH*NH*HP*NS
    float* Yb     = states + (size_t)BATCH*NCH*NH*HP*NS;  // TTOK*DI

    unsigned short* xb_bf  = (unsigned short*)Yb;                         // TTOK*DM
    unsigned short* ipw_bf = (unsigned short*)(Yb + (size_t)TTOK*DM/2);   // PROJ*DM
    unsigned short* opw_bf = (unsigned short*)states;                     // DM*DI (after y)
    unsigned short* Yb_bf  = (unsigned short*)xBCs;                       // TTOK*DI (after y)

    cast_bf16_k<<<(TTOK*DM)/(256*8), 256, 0, stream>>>(x, xb_bf, TTOK*DM);
    cast_bf16_k<<<(PROJ*DM)/(256*8), 256, 0, stream>>>(in_proj, ipw_bf, PROJ*DM);
    hgemm_nt<0><<<dim3((PROJ+127)/128, TTOK/128), 256, 0, stream>>>(xb_bf, ipw_bf, zx, nullptr, TTOK, PROJ, DM);
    conv_silu_k<<<(TTOK*CONVD)/256, 256, 0, stream>>>(zx, conv_w, xBCs);
    dtcuma_k<<<BATCH*NH*NCH/4, 256, 0, stream>>>(zx, dt_bias, A_log, dt_sp, cumA);
    cbt_k<<<BATCH*NCH, 256, 0, stream>>>(xBCs, CBTb);
    states_mfma_k<<<BATCH*NCH*NH, 256, 0, stream>>>(xBCs, dt_sp, cumA, states);
    scan_k<<<(BATCH*NH*HP*NS)/256, 256, 0, stream>>>(init_st, cumA, states, out + (size_t)TTOK*DM);
    y_mfma_k<<<BATCH*NCH*NH, 256, 0, stream>>>(xBCs, dt_sp, cumA, CBTb, states, D_param, Yb);
    cast_bf16_k<<<(DM*DI)/(256*8), 256, 0, stream>>>(out_proj, opw_bf, DM*DI);
    rms_gate_k<<<TTOK, 256, 0, stream>>>(zx, norm_w, Yb, Yb_bf);
    hgemm_nt<1><<<dim3(DM/128, TTOK/128), 256, 0, stream>>>(Yb_bf, opw_bf, out, x, TTOK, DM, DI);
}

// Round 5
// 329.536 us; speedup vs baseline: 3.2715x; 1.2023x over previous
//
#include <hip/hip_runtime.h>
#include <math.h>

#define BATCH 2
#define LSEQ  2048
#define TTOK  4096
#define DM    1024
#define DI    2048
#define NH    32
#define HP    64
#define NS    128
#define CONVD 2304
#define PROJ  4384
#define NCH   32
#define BLK   64

typedef __bf16 bf16x8 __attribute__((ext_vector_type(8)));
typedef float  f32x4  __attribute__((ext_vector_type(4)));
typedef unsigned short ushortx8 __attribute__((ext_vector_type(8)));
typedef unsigned short ushort_t;
typedef __attribute__((address_space(3))) void  lds_void;
typedef __attribute__((address_space(1))) const void glb_cvoid;

__device__ __forceinline__ float silu_(float x) { return x / (1.f + __expf(-x)); }

__device__ __forceinline__ unsigned short f2bf(float x) {
    union { float f; unsigned u; } u; u.f = x;
    unsigned r = u.u + 0x7fffu + ((u.u >> 16) & 1u);   // RNE
    return (unsigned short)(r >> 16);
}
__device__ __forceinline__ float bf2f(unsigned short s) {
    union { unsigned u; float f; } u; u.u = ((unsigned)s) << 16; return u.f;
}

// ---------------- fused cast: x, in_proj, out_proj -> bf16 ----------------
__global__ __launch_bounds__(256)
void cast_all_k(const float* __restrict__ x, const float* __restrict__ ipw,
                const float* __restrict__ opw,
                ushort_t* __restrict__ xb, ushort_t* __restrict__ ipb,
                ushort_t* __restrict__ opb)
{
    const int n1 = TTOK*DM, n2 = PROJ*DM;
    int i = (blockIdx.x * 256 + threadIdx.x) * 8;
    const float* src; ushort_t* dst;
    if (i < n1)            { src = x   + i;             dst = xb  + i; }
    else if (i < n1 + n2)  { src = ipw + (i - n1);      dst = ipb + (i - n1); }
    else                   { src = opw + (i - n1 - n2); dst = opb + (i - n1 - n2); }
    float4 a = *(const float4*)(src);
    float4 b = *(const float4*)(src + 4);
    ushortx8 r;
    r[0]=f2bf(a.x); r[1]=f2bf(a.y); r[2]=f2bf(a.z); r[3]=f2bf(a.w);
    r[4]=f2bf(b.x); r[5]=f2bf(b.y); r[6]=f2bf(b.z); r[7]=f2bf(b.w);
    *(ushortx8*)dst = r;
}

// ---------------- bf16 MFMA GEMM: C = A * Bw^T (+R). OUTBF: bf16 output ----------------
template<int HASRES, int OUTBF>
__global__ __launch_bounds__(256)
void hgemm_nt(const ushort_t* __restrict__ A, const ushort_t* __restrict__ Bw,
              void* __restrict__ Cp, const float* __restrict__ R,
              int M, int N, int K)
{
    __shared__ ushort_t As[128 * 32];
    __shared__ ushort_t Bs[128 * 32];
    const int t = threadIdx.x;
    const int l = t & 63, w = t >> 6;
    // 8-wide column-supertile swizzle for L2 locality
    const int tx_ = (N + 127) >> 7, ty_ = (M + 127) >> 7;
    int bid = blockIdx.x;
    int sc = bid / (8 * ty_), rem = bid % (8 * ty_);
    int sw_w = min(8, tx_ - sc * 8);
    int bx = sc * 8 + rem % sw_w;
    int by = rem / sw_w;
    const int bm = by * 128, bn = bx * 128;
    const int wm = (w >> 1) * 64, wn = (w & 1) * 64;

    const int srow = t >> 2;
    const int skk  = (t & 3) * 8;
    const ushort_t* Ag0 = A + (size_t)(bm + srow)      * K + skk;
    const ushort_t* Ag1 = A + (size_t)(bm + 64 + srow) * K + skk;
    const int bn0 = min(bn + srow, N - 1), bn1 = min(bn + 64 + srow, N - 1);
    const ushort_t* Bg0 = Bw + (size_t)bn0 * K + skk;
    const ushort_t* Bg1 = Bw + (size_t)bn1 * K + skk;
    char* As0 = (char*)As;
    char* Bs0 = (char*)Bs;
    const int la0 = 16 * t;
    const int la1 = 4096 + 16 * t;

    f32x4 acc[4][4] = {};
    const int fr = l & 15, koff = (l >> 4) * 8;

    for (int k0 = 0; k0 < K; k0 += 32) {
        __syncthreads();
        __builtin_amdgcn_global_load_lds((glb_cvoid*)(Ag0 + k0), (lds_void*)(As0 + la0), 16, 0, 0);
        __builtin_amdgcn_global_load_lds((glb_cvoid*)(Ag1 + k0), (lds_void*)(As0 + la1), 16, 0, 0);
        __builtin_amdgcn_global_load_lds((glb_cvoid*)(Bg0 + k0), (lds_void*)(Bs0 + la0), 16, 0, 0);
        __builtin_amdgcn_global_load_lds((glb_cvoid*)(Bg1 + k0), (lds_void*)(Bs0 + la1), 16, 0, 0);
        __syncthreads();
        bf16x8 af[4], bfr[4];
#pragma unroll
        for (int mt = 0; mt < 4; ++mt)
            af[mt] = *(const bf16x8*)(As + (wm + mt * 16 + fr) * 32 + koff);
#pragma unroll
        for (int nt = 0; nt < 4; ++nt)
            bfr[nt] = *(const bf16x8*)(Bs + (wn + nt * 16 + fr) * 32 + koff);
#pragma unroll
        for (int mt = 0; mt < 4; ++mt)
#pragma unroll
            for (int nt = 0; nt < 4; ++nt)
                acc[mt][nt] = __builtin_amdgcn_mfma_f32_16x16x32_bf16(af[mt], bfr[nt], acc[mt][nt], 0, 0, 0);
    }

    const int crow = (l >> 4) * 4, ccol = l & 15;
#pragma unroll
    for (int mt = 0; mt < 4; ++mt) {
#pragma unroll
        for (int nt = 0; nt < 4; ++nt) {
            int n = bn + wn + nt * 16 + ccol;
            if (n >= N) continue;
#pragma unroll
            for (int i = 0; i < 4; ++i) {
                int m = bm + wm + mt * 16 + crow + i;
                float v = acc[mt][nt][i];
                if (HASRES) v += R[(size_t)m * N + n];
                if (OUTBF) ((ushort_t*)Cp)[(size_t)m * N + n] = f2bf(v);
                else       ((float*)Cp)[(size_t)m * N + n] = v;
            }
        }
    }
}

// ---------------- fused: depthwise conv(K=4)+double silu  |  dt softplus + cumA scan ----------------
#define NCONVB 9216   // TTOK * (CONVD/4) / 256
__global__ __launch_bounds__(256)
void mid1_k(const ushort_t* __restrict__ zx, const float* __restrict__ cw,
            const float* __restrict__ dt_bias, const float* __restrict__ A_log,
            ushort_t* __restrict__ xBC, float* __restrict__ dt_sp, float* __restrict__ cumA)
{
    if (blockIdx.x < NCONVB) {
        int idx = blockIdx.x * 256 + threadIdx.x;
        int c4 = (idx % (CONVD/4)) * 4;
        int tkk = idx / (CONVD/4);
        int b = tkk >> 11, l = tkk & 2047;
        const ushort_t* col = zx + (size_t)b * LSEQ * PROJ + DI + c4;
        float4 w0 = *(const float4*)(cw + c4*4);
        float4 w1 = *(const float4*)(cw + c4*4 + 4);
        float4 w2 = *(const float4*)(cw + c4*4 + 8);
        float4 w3 = *(const float4*)(cw + c4*4 + 12);
        ushort4 tp = *(const ushort4*)(col + (size_t)l * PROJ);
        float a0 = w0.w * bf2f(tp.x), a1 = w1.w * bf2f(tp.y), a2 = w2.w * bf2f(tp.z), a3 = w3.w * bf2f(tp.w);
        if (l >= 1) { ushort4 v = *(const ushort4*)(col + (size_t)(l-1) * PROJ);
            a0 += w0.z*bf2f(v.x); a1 += w1.z*bf2f(v.y); a2 += w2.z*bf2f(v.z); a3 += w3.z*bf2f(v.w); }
        if (l >= 2) { ushort4 v = *(const ushort4*)(col + (size_t)(l-2) * PROJ);
            a0 += w0.y*bf2f(v.x); a1 += w1.y*bf2f(v.y); a2 += w2.y*bf2f(v.z); a3 += w3.y*bf2f(v.w); }
        if (l >= 3) { ushort4 v = *(const ushort4*)(col + (size_t)(l-3) * PROJ);
            a0 += w0.x*bf2f(v.x); a1 += w1.x*bf2f(v.y); a2 += w2.x*bf2f(v.z); a3 += w3.x*bf2f(v.w); }
        ushort4 o;
        o.x = f2bf(silu_(silu_(a0))); o.y = f2bf(silu_(silu_(a1)));
        o.z = f2bf(silu_(silu_(a2))); o.w = f2bf(silu_(silu_(a3)));
        *(ushort4*)(xBC + (size_t)tkk * CONVD + c4) = o;
    } else {
        int wid = (blockIdx.x - NCONVB) * 4 + (threadIdx.x >> 6);   // b*1024 + h*32 + c
        int ln = threadIdx.x & 63;
        int c = wid & 31, h = (wid >> 5) & 31, b = wid >> 10;
        int tk = b * LSEQ + c * BLK + ln;
        float xv = bf2f(zx[(size_t)tk * PROJ + (DI + CONVD) + h]) + dt_bias[h];
        float dtv = (xv > 20.f) ? xv : log1pf(__expf(xv));
        dt_sp[tk * NH + h] = dtv;
        float val = -__expf(A_log[h]) * dtv;
#pragma unroll
        for (int off = 1; off < 64; off <<= 1) {
            float u = __shfl_up(val, off, 64);
            if (ln >= off) val += u;
        }
        cumA[(size_t)wid * 64 + ln] = val;
    }
}

// ---------------- fused: CBT (64 blocks) | chunk-states MFMA (2048 blocks) ----------------
__global__ __launch_bounds__(256)
void mid2_k(const ushort_t* __restrict__ xBC, const float* __restrict__ dt_sp,
            const float* __restrict__ cumA, float* __restrict__ CBT,
            float* __restrict__ states)
{
    __shared__ __align__(16) char smem[33408];
    int t = threadIdx.x, r = t >> 2, q = t & 3;
    if (blockIdx.x < 64) {
        // CBT[l,s] = sum_n C[l,n]*B[s,n]
        int b = blockIdx.x >> 5, c = blockIdx.x & 31;
        float (*sB)[65] = (float(*)[65])smem;
        float (*sC)[65] = sB + 64;
        const ushort_t* xb = xBC + (size_t)(b * LSEQ + c * BLK) * CONVD;
        float acc[16];
#pragma unroll
        for (int i = 0; i < 16; ++i) acc[i] = 0.f;
        for (int half = 0; half < 2; ++half) {
            __syncthreads();
#pragma unroll
            for (int jj = 0; jj < 4; ++jj) {
                ushort4 bv = *(const ushort4*)(xb + (size_t)r * CONVD + DI      + half*64 + q*16 + jj*4);
                ushort4 cv = *(const ushort4*)(xb + (size_t)r * CONVD + DI + NS + half*64 + q*16 + jj*4);
                int col = q*16 + jj*4;
                sB[r][col]=bf2f(bv.x); sB[r][col+1]=bf2f(bv.y); sB[r][col+2]=bf2f(bv.z); sB[r][col+3]=bf2f(bv.w);
                sC[r][col]=bf2f(cv.x); sC[r][col+1]=bf2f(cv.y); sC[r][col+2]=bf2f(cv.z); sC[r][col+3]=bf2f(cv.w);
            }
            __syncthreads();
            for (int n = 0; n < 64; ++n) {
                float cv = sC[r][n];
#pragma unroll
                for (int si = 0; si < 16; ++si)
                    acc[si] += cv * sB[q*16 + si][n];
            }
        }
        float* o = CBT + (size_t)blockIdx.x * 4096 + r * 64 + q * 16;
#pragma unroll
        for (int si = 0; si < 16; ++si) o[si] = acc[si];
    } else {
        // S[p,n] = sum_l X[l,p] * (B[l,n]*dt[l]*dec[l])
        int bi = blockIdx.x - 64;            // b*1024 + c*32 + h
        int h = bi & 31, c = (bi >> 5) & 31, b = bi >> 10;
        ushort_t* XdT = (ushort_t*)smem;          // [p][l] stride 72
        ushort_t* BdT = XdT + 64 * 72;            // [n][l] stride 72
        const float* cA = cumA + (size_t)((b*NH + h)*NCH + c) * 64;
        float scale = dt_sp[(b * LSEQ + c * BLK + r) * NH + h] * __expf(cA[63] - cA[r]);
        const ushort_t* xb = xBC + (size_t)(b * LSEQ + c * BLK + r) * CONVD;
#pragma unroll
        for (int jj = 0; jj < 4; ++jj) {
            ushort4 v = *(const ushort4*)(xb + h*HP + q*16 + jj*4);
            int p0 = q*16 + jj*4;
            XdT[(p0+0)*72 + r] = v.x; XdT[(p0+1)*72 + r] = v.y;
            XdT[(p0+2)*72 + r] = v.z; XdT[(p0+3)*72 + r] = v.w;
        }
#pragma unroll
        for (int jj = 0; jj < 8; ++jj) {
            ushort4 v = *(const ushort4*)(xb + DI + q*32 + jj*4);
            int n0 = q*32 + jj*4;
            BdT[(n0+0)*72 + r] = f2bf(bf2f(v.x)*scale);
            BdT[(n0+1)*72 + r] = f2bf(bf2f(v.y)*scale);
            BdT[(n0+2)*72 + r] = f2bf(bf2f(v.z)*scale);
            BdT[(n0+3)*72 + r] = f2bf(bf2f(v.w)*scale);
        }
        __syncthreads();
        int ln = t & 63, w = t >> 6;
        int wm = (w >> 1) * 32, wn = (w & 1) * 64;
        int fr = ln & 15;
        f32x4 acc[2][4] = {};
#pragma unroll
        for (int ks = 0; ks < 2; ++ks) {
            int koff = ks*32 + (ln >> 4) * 8;
            bf16x8 af[2], bv[4];
#pragma unroll
            for (int mt = 0; mt < 2; ++mt) af[mt] = *(const bf16x8*)&XdT[(wm + mt*16 + fr)*72 + koff];
#pragma unroll
            for (int nt = 0; nt < 4; ++nt) bv[nt] = *(const bf16x8*)&BdT[(wn + nt*16 + fr)*72 + koff];
#pragma unroll
            for (int mt = 0; mt < 2; ++mt)
#pragma unroll
                for (int nt = 0; nt < 4; ++nt)
                    acc[mt][nt] = __builtin_amdgcn_mfma_f32_16x16x32_bf16(af[mt], bv[nt], acc[mt][nt], 0, 0, 0);
        }
        float* o = states + (size_t)((b*NCH + c)*NH + h) * 8192;
        int crow = (ln >> 4) * 4, ccol = ln & 15;
#pragma unroll
        for (int mt = 0; mt < 2; ++mt)
#pragma unroll
            for (int nt = 0; nt < 4; ++nt)
#pragma unroll
                for (int i = 0; i < 4; ++i)
                    o[(wm + mt*16 + crow + i)*128 + wn + nt*16 + ccol] = acc[mt][nt][i];
    }
}

// ---------------- inter-chunk scan: fp32 states in, bf16 prefix out + final fp32 ----------------
__global__ __launch_bounds__(256)
void scan_k(const float* __restrict__ init_state, const float* __restrict__ cumA,
            const float* __restrict__ states, ushort_t* __restrict__ pref,
            float* __restrict__ out_final)
{
    int idx = blockIdx.x * 256 + threadIdx.x;   // BATCH*NH*HP*NS
    int h = (idx >> 13) & 31, b = idx >> 18;
    int pn = idx & 8191;
    float run = init_state[idx];
    const float* cAb = cumA + (size_t)(b*NH + h) * NCH * 64;
    for (int c = 0; c < NCH; ++c) {
        float la = cAb[c*64 + 63];
        size_t off = (size_t)((b*NCH + c)*NH + h) * 8192 + pn;
        float tmp = states[off];
        pref[off] = f2bf(run);
        run = expf(la) * run + tmp;
    }
    out_final[idx] = run;
}

// ---------------- Y = Y_diag + Y_off + D*X via MFMA ----------------
__global__ __launch_bounds__(256)
void y_mfma_k(const ushort_t* __restrict__ xBC, const float* __restrict__ dt_sp,
              const float* __restrict__ cumA, const float* __restrict__ CBT,
              const ushort_t* __restrict__ pref, const float* __restrict__ D_param,
              float* __restrict__ Y)
{
    int bi = blockIdx.x;                 // b*1024 + c*32 + h
    int h = bi & 31, c = (bi >> 5) & 31, b = bi >> 10;
    __shared__ ushort_t Wm[64 * 72];     // [l][s] masked decay*CBT*dt[s]
    __shared__ ushort_t XT[64 * 72];     // [p][s] raw X
    __shared__ ushort_t Cd[64 * 136];    // [l][n] C*exp(cA)
    __shared__ ushort_t Sp[64 * 136];    // [p][n] bf16 prefix state
    __shared__ float sCA[64];
    __shared__ float sdt[64];
    int t = threadIdx.x, r = t >> 2, q = t & 3;
    const float* cA = cumA + (size_t)((b*NH + h)*NCH + c) * 64;
    if (t < 64) {
        sCA[t] = cA[t];
        sdt[t] = dt_sp[(b * LSEQ + c * BLK + t) * NH + h];
    }
    __syncthreads();
    size_t row = (size_t)(b * LSEQ + c * BLK + r);
    const ushort_t* xb = xBC + row * CONVD;
    float myA = sCA[r], eC = __expf(myA);
    const float* cbt = CBT + (size_t)(b*NCH + c) * 4096 + r * 64;
#pragma unroll
    for (int j = 0; j < 16; ++j) {
        int s = q*16 + j;
        float wv = (s <= r) ? cbt[s] * __expf(myA - sCA[s]) * sdt[s] : 0.f;
        Wm[r*72 + s] = f2bf(wv);
    }
#pragma unroll
    for (int jj = 0; jj < 4; ++jj) {
        ushort4 v = *(const ushort4*)(xb + h*HP + q*16 + jj*4);
        int p0 = q*16 + jj*4;
        XT[(p0+0)*72 + r] = v.x; XT[(p0+1)*72 + r] = v.y;
        XT[(p0+2)*72 + r] = v.z; XT[(p0+3)*72 + r] = v.w;
    }
#pragma unroll
    for (int jj = 0; jj < 8; ++jj) {
        ushort4 v = *(const ushort4*)(xb + DI + NS + q*32 + jj*4);
        int n0 = q*32 + jj*4;
        Cd[r*136 + n0+0] = f2bf(bf2f(v.x)*eC);
        Cd[r*136 + n0+1] = f2bf(bf2f(v.y)*eC);
        Cd[r*136 + n0+2] = f2bf(bf2f(v.z)*eC);
        Cd[r*136 + n0+3] = f2bf(bf2f(v.w)*eC);
    }
    const ushort_t* pr = pref + (size_t)((b*NCH + c)*NH + h) * 8192 + r * 128;
#pragma unroll
    for (int jj = 0; jj < 4; ++jj) {
        ushortx8 v = *(const ushortx8*)(pr + q*32 + jj*8);
        *(ushortx8*)&Sp[r*136 + q*32 + jj*8] = v;
    }
    __syncthreads();
    int ln = t & 63, w = t >> 6;
    int wm = (w >> 1) * 32, wn = (w & 1) * 32;   // l-span 32, p-span 32
    int fr = ln & 15;
    f32x4 acc[2][2] = {};
#pragma unroll
    for (int ks = 0; ks < 2; ++ks) {            // Y_diag over s (K=64)
        int koff = ks*32 + (ln >> 4) * 8;
        bf16x8 af[2], bv[2];
#pragma unroll
        for (int mt = 0; mt < 2; ++mt) af[mt] = *(const bf16x8*)&Wm[(wm + mt*16 + fr)*72 + koff];
#pragma unroll
        for (int nt = 0; nt < 2; ++nt) bv[nt] = *(const bf16x8*)&XT[(wn + nt*16 + fr)*72 + koff];
#pragma unroll
        for (int mt = 0; mt < 2; ++mt)
#pragma unroll
            for (int nt = 0; nt < 2; ++nt)
                acc[mt][nt] = __builtin_amdgcn_mfma_f32_16x16x32_bf16(af[mt], bv[nt], acc[mt][nt], 0, 0, 0);
    }
#pragma unroll
    for (int ks = 0; ks < 4; ++ks) {            // Y_off over n (K=128)
        int koff = ks*32 + (ln >> 4) * 8;
        bf16x8 af[2], bv[2];
#pragma unroll
        for (int mt = 0; mt < 2; ++mt) af[mt] = *(const bf16x8*)&Cd[(wm + mt*16 + fr)*136 + koff];
#pragma unroll
        for (int nt = 0; nt < 2; ++nt) bv[nt] = *(const bf16x8*)&Sp[(wn + nt*16 + fr)*136 + koff];
#pragma unroll
        for (int mt = 0; mt < 2; ++mt)
#pragma unroll
            for (int nt = 0; nt < 2; ++nt)
                acc[mt][nt] = __builtin_amdgcn_mfma_f32_16x16x32_bf16(af[mt], bv[nt], acc[mt][nt], 0, 0, 0);
    }
    float Dh = D_param[h];
    int crow = (ln >> 4) * 4, ccol = ln & 15;
#pragma unroll
    for (int mt = 0; mt < 2; ++mt)
#pragma unroll
        for (int nt = 0; nt < 2; ++nt)
#pragma unroll
            for (int i = 0; i < 4; ++i) {
                int li = wm + mt*16 + crow + i;
                int p  = wn + nt*16 + ccol;
                size_t rr = (size_t)(b*LSEQ + c*BLK + li);
                float xv = bf2f(xBC[rr * CONVD + h*HP + p]);
                Y[rr * DI + h*HP + p] = acc[mt][nt][i] + Dh * xv;
            }
}

// ---------------- RMSNorm + sigmoid(z) gate -> bf16 ----------------
__global__ __launch_bounds__(256)
void rms_gate_k(const ushort_t* __restrict__ zx, const float* __restrict__ norm_w,
                const float* __restrict__ Y, ushort_t* __restrict__ Yb)
{
    int tk = blockIdx.x, t = threadIdx.x;
    const float* rowp = Y + (size_t)tk * DI;
    float4 v0 = *(const float4*)(rowp + t*4);
    float4 v1 = *(const float4*)(rowp + 1024 + t*4);
    float ss = v0.x*v0.x + v0.y*v0.y + v0.z*v0.z + v0.w*v0.w
             + v1.x*v1.x + v1.y*v1.y + v1.z*v1.z + v1.w*v1.w;
#pragma unroll
    for (int off = 32; off > 0; off >>= 1) ss += __shfl_xor(ss, off, 64);
    __shared__ float sw[4];
    __shared__ float stot;
    if ((t & 63) == 0) sw[t >> 6] = ss;
    __syncthreads();
    if (t == 0) stot = rsqrtf((sw[0]+sw[1]+sw[2]+sw[3]) * (1.f/DI) + 1.1920929e-07f);
    __syncthreads();
    float scale = stot;
    const ushort_t* zr = zx + (size_t)tk * PROJ;
    ushort4 z0 = *(const ushort4*)(zr + t*4);
    ushort4 z1 = *(const ushort4*)(zr + 1024 + t*4);
    float4 w0 = *(const float4*)(norm_w + t*4);
    float4 w1 = *(const float4*)(norm_w + 1024 + t*4);
    ushort4 o0, o1;
    o0.x = f2bf(v0.x*scale*w0.x / (1.f+__expf(-bf2f(z0.x))));
    o0.y = f2bf(v0.y*scale*w0.y / (1.f+__expf(-bf2f(z0.y))));
    o0.z = f2bf(v0.z*scale*w0.z / (1.f+__expf(-bf2f(z0.z))));
    o0.w = f2bf(v0.w*scale*w0.w / (1.f+__expf(-bf2f(z0.w))));
    o1.x = f2bf(v1.x*scale*w1.x / (1.f+__expf(-bf2f(z1.x))));
    o1.y = f2bf(v1.y*scale*w1.y / (1.f+__expf(-bf2f(z1.y))));
    o1.z = f2bf(v1.z*scale*w1.z / (1.f+__expf(-bf2f(z1.z))));
    o1.w = f2bf(v1.w*scale*w1.w / (1.f+__expf(-bf2f(z1.w))));
    *(ushort4*)(Yb + (size_t)tk * DI + t*4) = o0;
    *(ushort4*)(Yb + (size_t)tk * DI + 1024 + t*4) = o1;
}

extern "C" void kernel_launch(void* const* d_in, const int* in_sizes, int n_in,
                              void* d_out, int out_size, void* d_ws, size_t ws_size,
                              hipStream_t stream)
{
    const float* x        = (const float*)d_in[0];
    const float* init_st  = (const float*)d_in[1];
    const float* in_proj  = (const float*)d_in[2];
    const float* conv_w   = (const float*)d_in[3];
    const float* A_log    = (const float*)d_in[4];
    const float* dt_bias  = (const float*)d_in[5];
    const float* D_param  = (const float*)d_in[6];
    const float* norm_w   = (const float*)d_in[7];
    const float* out_proj = (const float*)d_in[8];
    float* out = (float*)d_out;

    ushort_t* zx_bf  = (ushort_t*)d_ws;                       // TTOK*PROJ
    ushort_t* xBC_bf = zx_bf + (size_t)TTOK*PROJ;             // TTOK*CONVD
    float* dt_sp  = (float*)(xBC_bf + (size_t)TTOK*CONVD);    // TTOK*NH
    float* cumA   = dt_sp  + (size_t)TTOK*NH;                 // 131072
    float* CBTb   = cumA   + (size_t)TTOK*NH;                 // 262144
    float* states = CBTb   + 262144;                          // 16777216 (fp32)
    ushort_t* pref = (ushort_t*)(states + 16777216);          // 16777216 (bf16)
    float* Y      = (float*)(pref + 16777216);                // TTOK*DI fp32
    ushort_t* opw_bf = (ushort_t*)(Y + (size_t)TTOK*DI);      // DM*DI
    // aliases: gemm1 inputs live in Y's region (dead until y_mfma)
    ushort_t* xb_bf  = (ushort_t*)Y;                          // TTOK*DM
    ushort_t* ipw_bf = xb_bf + (size_t)TTOK*DM;               // PROJ*DM
    ushort_t* Yb_bf  = xBC_bf;                                // alias, used after y_mfma

    const int nc = (TTOK*DM + PROJ*DM + DM*DI) / (256*8);
    cast_all_k<<<nc, 256, 0, stream>>>(x, in_proj, out_proj, xb_bf, ipw_bf, opw_bf);
    hgemm_nt<0,1><<<((PROJ+127)/128)*(TTOK/128), 256, 0, stream>>>(xb_bf, ipw_bf, zx_bf, nullptr, TTOK, PROJ, DM);
    mid1_k<<<NCONVB + BATCH*NH*NCH/4, 256, 0, stream>>>(zx_bf, conv_w, dt_bias, A_log, xBC_bf, dt_sp, cumA);
    mid2_k<<<64 + BATCH*NCH*NH, 256, 0, stream>>>(xBC_bf, dt_sp, cumA, CBTb, states);
    scan_k<<<(BATCH*NH*HP*NS)/256, 256, 0, stream>>>(init_st, cumA, states, pref, out + (size_t)TTOK*DM);
    y_mfma_k<<<BATCH*NCH*NH, 256, 0, stream>>>(xBC_bf, dt_sp, cumA, CBTb, pref, D_param, Y);
    rms_gate_k<<<TTOK, 256, 0, stream>>>(zx_bf, norm_w, Y, Yb_bf);
    hgemm_nt<1,0><<<(DM/128)*(TTOK/128), 256, 0, stream>>>(Yb_bf, opw_bf, out, x, TTOK, DM, DI);
}